// Round 7
// baseline (210.817 us; speedup 1.0000x reference)
//
#include <hip/hip_runtime.h>
#include <hip/hip_bf16.h>

typedef __bf16 bf16x8 __attribute__((ext_vector_type(8)));
typedef float f32x4 __attribute__((ext_vector_type(4)));
typedef unsigned short u16;

__device__ __forceinline__ u16 f2bf(float f) {
    union { float f; unsigned u; } x{f};
    unsigned r = x.u + 0x7fffu + ((x.u >> 16) & 1u);
    return (u16)(r >> 16);
}
// fast round-half-up pack of two fp32 -> packed bf16x2 (P >= 0, never NaN/Inf)
__device__ __forceinline__ unsigned pk2(float a, float b) {
    union { float f; unsigned u; } x{a}, y{b};
    return ((x.u + 0x8000u) >> 16) | ((y.u + 0x8000u) & 0xffff0000u);
}
// hardware exp2 (v_exp_f32); avoids glibc __exp2f macro collision
__device__ __forceinline__ float ex2(float x) { return __builtin_amdgcn_exp2f(x); }
__device__ __forceinline__ f32x4 zero4() { f32x4 z = {0.f, 0.f, 0.f, 0.f}; return z; }

// async global->LDS, 16B per lane; HW writes lane i at ldsbase + i*16
typedef const __attribute__((address_space(1))) unsigned int* gp1_t;
typedef __attribute__((address_space(3))) unsigned int* lp3_t;
__device__ __forceinline__ void async16(const u16* g, u16* l) {
    __builtin_amdgcn_global_load_lds((gp1_t)g, (lp3_t)l, 16, 0, 0);
}

// ======== prep: fused cast(hs->bf16) + W transposes + rope cos/sin tables ========
// blocks [0,4096): cast; [4096,7168): Wqkv^T (N-permuted for 8-phase gemm_qkv);
// [7168,8192): Wo^T; [8192,8448): tables
// Wqkvt perm (within each 256-col tile): orig (head hh, 16-frag f) -> position
// (f>>1)*8 + hh*2 + (f&1). Makes each gemm wave own one head with frag order
// f0,f1,f2,f3 at j=0..3 -> rope pairs (d, d+32) stay wave-local.
__global__ void __launch_bounds__(256) prep(const float* __restrict__ hs,
                                            u16* __restrict__ Xb,
                                            const float* __restrict__ Wqkv,
                                            u16* __restrict__ Wqkvt,
                                            const float* __restrict__ Wo,
                                            u16* __restrict__ Wot,
                                            float* __restrict__ cosT,
                                            float* __restrict__ sinT) {
    __shared__ float tile[32][33];
    const int blk = blockIdx.x, t = threadIdx.x;
    if (blk < 4096) {                       // cast 4096*1024 fp32 -> bf16
        int i = (blk * 256 + t) * 4;
        float4 v = *(const float4*)(hs + i);
        ushort4 o;
        o.x = f2bf(v.x); o.y = f2bf(v.y); o.z = f2bf(v.z); o.w = f2bf(v.w);
        *(ushort4*)(Xb + i) = o;
    } else if (blk < 8192) {                // transpose+cast W[K][N] -> Wt[N][K]
        const float* W; u16* Wt; int N, bx, by;
        bool qkv = (blk < 7168);
        if (qkv) { int bid = blk - 4096; W = Wqkv; Wt = Wqkvt; N = 3072; bx = bid % 96; by = bid / 96; }
        else     { int bid = blk - 7168; W = Wo;   Wt = Wot;   N = 1024; bx = bid % 32; by = bid / 32; }
        const int K = 1024;
        int tx = t & 31, ty = t >> 5;
        int n0 = bx * 32, k0 = by * 32;
#pragma unroll
        for (int i = 0; i < 32; i += 8)
            tile[ty + i][tx] = W[(size_t)(k0 + ty + i) * N + n0 + tx];
        __syncthreads();
#pragma unroll
        for (int i = 0; i < 32; i += 8) {
            int n = n0 + ty + i;
            int np = n;
            if (qkv) {
                int hh = (n >> 6) & 3, f = (n >> 4) & 3;
                np = (n & ~255) | (((f >> 1) * 8 + hh * 2 + (f & 1)) << 4) | (n & 15);
            }
            Wt[(size_t)np * K + k0 + tx] = f2bf(tile[tx][ty + i]);
        }
    } else {                                // rope tables: [2048][32] fp32
        int idx = (blk - 8192) * 256 + t;   // 65536
        int d = idx & 31, s = idx >> 5;
        float inv = expf(-(float)d * 0.374466538f);   // ln(160000)/32
        float th = (float)s * inv;
        cosT[idx] = cosf(th);
        sinT[idx] = sinf(th);
    }
}

// ======== 4-wave 128x128 GEMM K-loop (kept for gemm_out) ========
struct GemmCtx {
    f32x4 acc[4][4];
    int m16, q4, wm, wn;
};
template <int KDIM>
__device__ __forceinline__ void gemm_loop(const u16* __restrict__ A,
                                          const u16* __restrict__ Bt,
                                          int bm, int bn, GemmCtx& cx,
                                          u16* As, u16* Bs) {   // each [3][128*32]
    const int t = threadIdx.x;
    const int lane = t & 63, w = t >> 6;
    cx.wm = w >> 1; cx.wn = w & 1;
    cx.m16 = lane & 15; cx.q4 = lane >> 4;

    const int lrow = lane >> 2;
    const int kchunk = (lane & 3) ^ ((lane >> 3) & 3);   // swizzled global gather
    const u16* Ag = A + (size_t)(bm * 128 + w * 32 + lrow) * KDIM + kchunk * 8;
    const u16* Bg = Bt + (size_t)(bn * 128 + w * 32 + lrow) * KDIM + kchunk * 8;
    const int l0 = (w * 32) * 32;
    const int l1 = (w * 32 + 16) * 32;
    const int kswz = (cx.q4 ^ ((cx.m16 >> 1) & 3)) * 8;

#pragma unroll
    for (int i = 0; i < 4; i++)
#pragma unroll
        for (int j = 0; j < 4; j++) cx.acc[i][j] = zero4();

    constexpr int NT = KDIM / 32;
    // prologue: stage tiles 0,1 into buffers 0,1
    async16(Ag, As + l0);
    async16(Ag + 16 * KDIM, As + l1);
    async16(Bg, Bs + l0);
    async16(Bg + 16 * KDIM, Bs + l1);
    async16(Ag + 32, As + 4096 + l0);
    async16(Ag + 16 * KDIM + 32, As + 4096 + l1);
    async16(Bg + 32, Bs + 4096 + l0);
    async16(Bg + 16 * KDIM + 32, Bs + 4096 + l1);

    int co = 0, po = 2 * 4096;               // current / prefetch-dest buffer offsets
#pragma unroll 1
    for (int tt = 0; tt < NT; ++tt) {
        if (tt + 1 < NT) {
            asm volatile("s_waitcnt vmcnt(4)" ::: "memory");  // tile t landed
        } else {
            asm volatile("s_waitcnt vmcnt(0)" ::: "memory");
        }
        __builtin_amdgcn_s_barrier();
        __builtin_amdgcn_sched_barrier(0);
        if (tt + 2 < NT) {
            const int k0 = (tt + 2) * 32;
            async16(Ag + k0, As + po + l0);
            async16(Ag + 16 * KDIM + k0, As + po + l1);
            async16(Bg + k0, Bs + po + l0);
            async16(Bg + 16 * KDIM + k0, Bs + po + l1);
        }
        __builtin_amdgcn_sched_barrier(0);

        bf16x8 af[4], bf[4];
#pragma unroll
        for (int i = 0; i < 4; i++)
            af[i] = *(const bf16x8*)&As[co + (cx.wm * 64 + i * 16 + cx.m16) * 32 + kswz];
#pragma unroll
        for (int j = 0; j < 4; j++)
            bf[j] = *(const bf16x8*)&Bs[co + (cx.wn * 64 + j * 16 + cx.m16) * 32 + kswz];
#pragma unroll
        for (int i = 0; i < 4; i++)
#pragma unroll
            for (int j = 0; j < 4; j++)
                cx.acc[i][j] = __builtin_amdgcn_mfma_f32_16x16x32_bf16(af[i], bf[j], cx.acc[i][j], 0, 0, 0);

        asm volatile("" ::: "memory");
        __builtin_amdgcn_sched_barrier(0);
        co += 4096; if (co == 12288) co = 0;
        po += 4096; if (po == 12288) po = 0;
    }
}

// ======== gemm_qkv: 256^2, BK=64, 8 waves, 8-PHASE fine interleave (T2+T3+T4+T5) ====
// Each K-tile = 4 sub-phases {ds_read subtile || stage 1 half-tile -> barrier ->
// 16 MFMA (setprio) -> barrier}. A-frags live 2 phases, B-frags live whole tile ->
// LDS reads stay at 24/wave/tile. Stage schedule (into buf[T&1] / other buf):
// q0: A-high(T+1), q1: B-high(T+1), q2: A-low(T+2), q3: B-low(T+2) + vmcnt(4).
// Swizzle: LDS slot s of row r holds global k-chunk s ^ (r&7) (lane-local gather
// pre-swizzle); read slot = (ks*4+q4) ^ (m16&7) -> conflict-free (R4: conflicts=0).
__global__ void __launch_bounds__(512, 2) gemm_qkv(const u16* __restrict__ A,
                                                   const u16* __restrict__ Bt,
                                                   const float* __restrict__ cosT,
                                                   const float* __restrict__ sinT,
                                                   u16* __restrict__ Q,
                                                   u16* __restrict__ Kd,
                                                   u16* __restrict__ Vt) {
    __shared__ __align__(16) u16 As[2 * 256 * 64];
    __shared__ __align__(16) u16 Bs[2 * 256 * 64];
    constexpr int HB = 256 * 64;
    const int t = threadIdx.x, lane = t & 63, w = t >> 6;
    const int wm = w >> 2, wn = w & 3;
    const int m16 = lane & 15, q4 = lane >> 4, m7 = m16 & 7;
    const int hw = blockIdx.x;
    const int orig = (hw & 7) * 24 + (hw >> 3);   // bijective XCD swizzle: 192 = 8*24
    const int bm = orig / 12, bn = orig % 12;

    const int srow = lane >> 3;
    const int schunk = (lane & 7) ^ srow;
    const u16* Ag = A + (size_t)(bm * 256 + w * 8 + srow) * 1024 + schunk * 8;
    const u16* Bg = Bt + (size_t)(bn * 256 + w * 8 + srow) * 1024 + schunk * 8;
    u16* AsW = As + w * 512;     // wave's 8-row stage slab base
    u16* BsW = Bs + w * 512;

    f32x4 acc[8][4];
#pragma unroll
    for (int i = 0; i < 8; i++)
#pragma unroll
        for (int j = 0; j < 4; j++) acc[i][j] = zero4();

    const int slt0 = (q4 ^ m7) * 8;          // ks=0 read slot (u16 units)
    const int slt1 = ((4 + q4) ^ m7) * 8;    // ks=1

// stage one half-tile (2 async16/thread): half H of K-tile S, operand A/B
#define STGA(S, H) do { const u16* g_ = Ag + (size_t)(H) * 131072 + (S) * 64; \
    u16* l_ = AsW + ((S) & 1) * HB + (H) * 8192; \
    async16(g_, l_); async16(g_ + 65536, l_ + 4096); } while (0)
#define STGB(S, H) do { const u16* g_ = Bg + (size_t)(H) * 131072 + (S) * 64; \
    u16* l_ = BsW + ((S) & 1) * HB + (H) * 8192; \
    async16(g_, l_); async16(g_ + 65536, l_ + 4096); } while (0)

    // prologue: tile0 all 4 halves + tile1 A-low, B-low (12 loads/thread)
    STGA(0, 0); STGB(0, 0); STGA(0, 1); STGB(0, 1); STGA(1, 0); STGB(1, 0);
    asm volatile("s_waitcnt vmcnt(4)" ::: "memory");   // tile 0 landed
    __builtin_amdgcn_sched_barrier(0);
    __builtin_amdgcn_s_barrier();

#define MFMA8(IB, B0, B1) do { \
    _Pragma("unroll") for (int i4 = 0; i4 < 4; i4++) \
    _Pragma("unroll") for (int j2 = 0; j2 < 2; j2++) \
        acc[(IB) + i4][(JB) + j2] = __builtin_amdgcn_mfma_f32_16x16x32_bf16(a0[i4], B0[j2], acc[(IB) + i4][(JB) + j2], 0, 0, 0); \
    _Pragma("unroll") for (int i4 = 0; i4 < 4; i4++) \
    _Pragma("unroll") for (int j2 = 0; j2 < 2; j2++) \
        acc[(IB) + i4][(JB) + j2] = __builtin_amdgcn_mfma_f32_16x16x32_bf16(a1[i4], B1[j2], acc[(IB) + i4][(JB) + j2], 0, 0, 0); \
} while (0)

#define BAR1() do { __builtin_amdgcn_sched_barrier(0); __builtin_amdgcn_s_barrier(); \
                    __builtin_amdgcn_s_setprio(1); } while (0)
#define BAR2() do { __builtin_amdgcn_s_setprio(0); asm volatile("" ::: "memory"); \
                    __builtin_amdgcn_sched_barrier(0); __builtin_amdgcn_s_barrier(); } while (0)

#pragma unroll 1
    for (int T = 0; T < 16; ++T) {
        const int co = (T & 1) * HB;
        const int aL = co + (wm * 64 + m16) * 64;
        const int aH = aL + 128 * 64;
        const int bL = co + (wn * 32 + m16) * 64;
        const int bH = bL + 128 * 64;
        bf16x8 a0[4], a1[4], pl0[2], pl1[2], ph0[2], ph1[2];

        // ---- q0: read A-low + B-low; stage A-high(T+1); MFMA quad (lowA, lowB) ----
#pragma unroll
        for (int i4 = 0; i4 < 4; i4++) {
            a0[i4] = *(const bf16x8*)&As[aL + i4 * 1024 + slt0];
            a1[i4] = *(const bf16x8*)&As[aL + i4 * 1024 + slt1];
        }
#pragma unroll
        for (int j2 = 0; j2 < 2; j2++) {
            pl0[j2] = *(const bf16x8*)&Bs[bL + j2 * 1024 + slt0];
            pl1[j2] = *(const bf16x8*)&Bs[bL + j2 * 1024 + slt1];
        }
        if (T < 15) STGA(T + 1, 1);
        BAR1();
        { constexpr int JB = 0; MFMA8(0, pl0, pl1); }
        BAR2();

        // ---- q1: read B-high; stage B-high(T+1); MFMA (lowA, highB) reusing a0/a1 ----
#pragma unroll
        for (int j2 = 0; j2 < 2; j2++) {
            ph0[j2] = *(const bf16x8*)&Bs[bH + j2 * 1024 + slt0];
            ph1[j2] = *(const bf16x8*)&Bs[bH + j2 * 1024 + slt1];
        }
        if (T < 15) STGB(T + 1, 1);
        BAR1();
        { constexpr int JB = 2; MFMA8(0, ph0, ph1); }
        BAR2();

        // ---- q2: reload A-high; stage A-low(T+2); MFMA (highA, lowB) reusing pl ----
#pragma unroll
        for (int i4 = 0; i4 < 4; i4++) {
            a0[i4] = *(const bf16x8*)&As[aH + i4 * 1024 + slt0];
            a1[i4] = *(const bf16x8*)&As[aH + i4 * 1024 + slt1];
        }
        if (T < 14) STGA(T + 2, 0);
        BAR1();
        { constexpr int JB = 0; MFMA8(4, pl0, pl1); }
        BAR2();

        // ---- q3: no reads; stage B-low(T+2) + vmcnt; MFMA (highA, highB) ----
        if (T < 14) {
            STGB(T + 2, 0);
            asm volatile("s_waitcnt vmcnt(4)" ::: "memory");  // tile T+1 landed
        } else {
            asm volatile("s_waitcnt vmcnt(0)" ::: "memory");
        }
        BAR1();
        { constexpr int JB = 2; MFMA8(4, ph0, ph1); }
        BAR2();
    }
#undef STGA
#undef STGB
#undef MFMA8
#undef BAR1
#undef BAR2

    // ==== epilogue: wave = one (type, head) via virtual colbase (perm baked in W) ====
    const int colbase = bn * 256 + wn * 64;
    const int type = colbase >> 10;            // 0=Q 1=K 2=V
    const int h = (colbase & 1023) >> 6;

    if (type == 2) {
        // V transposed: Vt[bh][d][s]; lane's rr=0..3 are 4 consecutive s -> 8B store
#pragma unroll
        for (int i = 0; i < 8; i++) {
            int sr = bm * 256 + (i >> 2) * 128 + wm * 64 + (i & 3) * 16 + q4 * 4;
            int b = sr >> 11, sl = sr & 2047;
            size_t ob = (size_t)(b * 16 + h) * 64 * 2048;
#pragma unroll
            for (int j = 0; j < 4; j++) {
                int d = j * 16 + m16;
                ushort4 o;
                o.x = f2bf(acc[i][j][0]);
                o.y = f2bf(acc[i][j][1]);
                o.z = f2bf(acc[i][j][2]);
                o.w = f2bf(acc[i][j][3]);
                *(ushort4*)&Vt[ob + (size_t)d * 2048 + sl] = o;
            }
        }
    } else {
        u16* dst = (type == 0) ? Q : Kd;
        const float qs = (type == 0) ? 0.1803368801f /*0.125*log2(e)*/ : 1.0f;
#pragma unroll
        for (int i = 0; i < 8; i++)
#pragma unroll
            for (int rr = 0; rr < 4; rr++) {
                int r = bm * 256 + (i >> 2) * 128 + wm * 64 + (i & 3) * 16 + q4 * 4 + rr;
                int b = r >> 11, s = r & 2047;
                size_t ob = ((size_t)((b * 16 + h) * 2048 + s)) * 64;
#pragma unroll
                for (int j2 = 0; j2 < 2; j2++) {
                    int d = j2 * 16 + m16;                 // d in [0,32)
                    float cs = cosT[s * 32 + d];
                    float sn = sinT[s * 32 + d];
                    float x1 = acc[i][j2][rr];
                    float x2 = acc[i][j2 + 2][rr];
                    dst[ob + d]      = f2bf((x1 * cs - x2 * sn) * qs);
                    dst[ob + d + 32] = f2bf((x2 * cs + x1 * sn) * qs);
                }
            }
    }
}

// ---------------- out-proj GEMM: C[M,N] fp32 = A[M,K] @ Bt[N,K]^T ----------------
__global__ void __launch_bounds__(256) gemm_out(const u16* __restrict__ A,
                                                const u16* __restrict__ Bt,
                                                float* __restrict__ C) {
    __shared__ __align__(16) u16 As[3 * 128 * 32];
    __shared__ __align__(16) u16 Bs[3 * 128 * 32];
    GemmCtx cx;
    const int bm = blockIdx.y, bn = blockIdx.x;
    gemm_loop<1024>(A, Bt, bm, bn, cx, As, Bs);
    const int N = 1024;
#pragma unroll
    for (int i = 0; i < 4; i++)
#pragma unroll
        for (int j = 0; j < 4; j++)
#pragma unroll
            for (int rr = 0; rr < 4; rr++) {
                int row = bm * 128 + cx.wm * 64 + i * 16 + cx.q4 * 4 + rr;
                int col = bn * 128 + cx.wn * 64 + j * 16 + cx.m16;
                C[(size_t)row * N + col] = cx.acc[i][j][rr];
            }
}

// ---------------- causal flash attention v2: 256 thr, 4 waves, operand-reuse split ----
// grid (8, B*nh): block bx handles supertile pair {bx, 15-bx} (34 staged tiles).
// QK^T: wave w owns 16-KEY slice, all 128 q in regs (qf[8][2]) -> K-frags read once,
// reused x8. PV: wave w owns 32-q slice x all 64 d -> vf reused x2, pf x4.
// P redistributed via Pt[128][72] LDS (XOR-granule swizzle: slot = g ^ (row&7),
// the pattern measured conflict-free in gemm_qkv). K/V LDS [64][64] same swizzle.
// Fixed-max softmax p = 2^(s'-24); li deferred: per-wave partials in regs, one
// cross-wave LDS reduce at phase end. Two barriers/tile (stage publish, P publish).
__global__ void __launch_bounds__(256) attn_kernel(const u16* __restrict__ Q,
                                                   const u16* __restrict__ Kg_,
                                                   const u16* __restrict__ Vtg_,
                                                   u16* __restrict__ O) {
    __shared__ __align__(16) u16 Ks[2][64][64];     // [buf][key][d]   swizzled
    __shared__ __align__(16) u16 Vs[2][64][64];     // [buf][d][key]   swizzled
    __shared__ __align__(16) u16 Pt[128][72];       // [q][key] pad+swizzled
    __shared__ float Li[4][128];                    // per-wave li partials
    const int t = threadIdx.x, w = t >> 6, lane = t & 63;
    const int m16 = lane & 15, q4 = lane >> 4, m7 = m16 & 7;
    const int bx = blockIdx.x, bh = blockIdx.y;
    const size_t base = (size_t)bh * 2048 * 64;
    const int b = bh >> 4, h = bh & 15;
    // staging: thread t covers row kr (key for K, d for V), granules {kc, kc+4}
    const int kr = t >> 2, kc = t & 3;
    const int wg0 = (kc ^ (kr & 7)) * 8;            // swizzled LDS u16 offsets
    const int wg1 = ((kc + 4) ^ (kr & 7)) * 8;

#pragma unroll 1
    for (int ph = 0; ph < 2; ph++) {
        const int st = ph ? (15 - bx) : bx;
        // Q fragments for ALL 128 q-rows of this supertile (B-operand: lane m16 = q-col)
        bf16x8 qf[8][2];
        const u16* Qg = Q + base + (size_t)(st * 128 + m16) * 64 + q4 * 8;
#pragma unroll
        for (int qb = 0; qb < 8; qb++) {
            qf[qb][0] = *(const bf16x8*)(Qg + qb * 16 * 64);
            qf[qb][1] = *(const bf16x8*)(Qg + qb * 16 * 64 + 32);
        }

        f32x4 occ[2][4];
#pragma unroll
        for (int qb2 = 0; qb2 < 2; qb2++)
#pragma unroll
            for (int db = 0; db < 4; db++) occ[qb2][db] = zero4();
        float li[8];
#pragma unroll
        for (int qb = 0; qb < 8; qb++) li[qb] = 0.f;

        const int jtmax = 2 * st + 1;
        const u16* Kb0 = Kg_ + base + (size_t)kr * 64 + kc * 8;      // + jt*4096
        const u16* Vb0 = Vtg_ + base + (size_t)kr * 2048 + kc * 8;   // + jt*64
        uint4 ka0 = *(const uint4*)(Kb0);
        uint4 ka1 = *(const uint4*)(Kb0 + 32);
        uint4 va0 = *(const uint4*)(Vb0);
        uint4 va1 = *(const uint4*)(Vb0 + 32);

#pragma unroll 1
        for (int jt = 0; jt <= jtmax; jt++) {
            const int bi = jt & 1;
            *(uint4*)&Ks[bi][kr][wg0] = ka0;
            *(uint4*)&Ks[bi][kr][wg1] = ka1;
            *(uint4*)&Vs[bi][kr][wg0] = va0;
            *(uint4*)&Vs[bi][kr][wg1] = va1;
            if (jt < jtmax) {
                const u16* kn = Kb0 + (size_t)(jt + 1) * 4096;
                const u16* vn = Vb0 + (jt + 1) * 64;
                ka0 = *(const uint4*)(kn);
                ka1 = *(const uint4*)(kn + 32);
                va0 = *(const uint4*)(vn);
                va1 = *(const uint4*)(vn + 32);
            }
            __syncthreads();   // stage visible

            // ---- QK^T: wave w owns keys 16w..16w+15; kf read once, reused x8 qb ----
            bf16x8 kf0 = *(const bf16x8*)&Ks[bi][w * 16 + m16][(q4 ^ m7) * 8];
            bf16x8 kf1 = *(const bf16x8*)&Ks[bi][w * 16 + m16][((4 + q4) ^ m7) * 8];
            const int keyb = 64 * jt + 16 * w + 4 * q4;   // + rr
            const bool dm = (jt >= 2 * st);
            const int pg = (2 * w + (q4 >> 1)) ^ m7;      // Pt write granule
            const int po = pg * 8 + (q4 & 1) * 4;
#pragma unroll
            for (int qb = 0; qb < 8; qb++) {
                f32x4 stv = zero4();
                stv = __builtin_amdgcn_mfma_f32_16x16x32_bf16(kf0, qf[qb][0], stv, 0, 0, 0);
                stv = __builtin_amdgcn_mfma_f32_16x16x32_bf16(kf1, qf[qb][1], stv, 0, 0, 0);
                const int qg = st * 128 + qb * 16 + m16;
                float p[4];
#pragma unroll
                for (int rr = 0; rr < 4; rr++) {
                    float s = stv[rr];
                    if (dm && (keyb + rr > qg)) s = -1e30f;
                    p[rr] = ex2(s - 24.f);
                }
                li[qb] += (p[0] + p[1]) + (p[2] + p[3]);
                *(uint2*)&Pt[qb * 16 + m16][po] = make_uint2(pk2(p[0], p[1]), pk2(p[2], p[3]));
            }
            __syncthreads();   // P visible (also fences prior PV reads of Pt)

            // ---- PV: wave w owns q in [32w, 32w+32); vf reused x2 qb2, pf x4 db ----
#pragma unroll
            for (int kh = 0; kh < 2; kh++) {
                const int gs = ((kh * 4 + q4) ^ m7) * 8;
                bf16x8 pf[2], vf[4];
#pragma unroll
                for (int qb2 = 0; qb2 < 2; qb2++)
                    pf[qb2] = *(const bf16x8*)&Pt[w * 32 + qb2 * 16 + m16][gs];
#pragma unroll
                for (int db = 0; db < 4; db++)
                    vf[db] = *(const bf16x8*)&Vs[bi][db * 16 + m16][gs];
#pragma unroll
                for (int qb2 = 0; qb2 < 2; qb2++)
#pragma unroll
                    for (int db = 0; db < 4; db++)
                        occ[qb2][db] = __builtin_amdgcn_mfma_f32_16x16x32_bf16(pf[qb2], vf[db], occ[qb2][db], 0, 0, 0);
            }
        }

        // ---- li: reduce over q4 lanes, publish per-wave partial, sum 4 waves ----
#pragma unroll
        for (int qb = 0; qb < 8; qb++) {
            li[qb] += __shfl_xor(li[qb], 16);
            li[qb] += __shfl_xor(li[qb], 32);
        }
        if (lane < 16) {
#pragma unroll
            for (int qb = 0; qb < 8; qb++) Li[w][qb * 16 + m16] = li[qb];
        }
        __syncthreads();

        // ---- epilogue: lane q-rows = 32w + qb2*16 + 4q4 + rr, d-col = db*16 + m16 ----
#pragma unroll
        for (int qb2 = 0; qb2 < 2; qb2++)
#pragma unroll
            for (int rr = 0; rr < 4; rr++) {
                int ql = w * 32 + qb2 * 16 + q4 * 4 + rr;
                float rli = 1.0f / (Li[0][ql] + Li[1][ql] + Li[2][ql] + Li[3][ql]);
                int qgl = st * 128 + ql;
                u16* Op = O + ((size_t)(b * 2048 + qgl)) * 1024 + h * 64 + m16;
#pragma unroll
                for (int db = 0; db < 4; db++)
                    Op[db * 16] = f2bf(occ[qb2][db][rr] * rli);
            }
        __syncthreads();  // protect LDS across phase boundary
    }
}

extern "C" void kernel_launch(void* const* d_in, const int* in_sizes, int n_in,
                              void* d_out, int out_size, void* d_ws, size_t ws_size,
                              hipStream_t stream) {
    const float* hs   = (const float*)d_in[0];
    const float* Wqkv = (const float*)d_in[2];
    const float* Wo   = (const float*)d_in[3];
    float* out = (float*)d_out;

    const int BS = 4096;
    const int H = 1024, N3 = 3072;
    const int SH = 32 * 2048 * 64;

    u16* Xb    = (u16*)d_ws;                 // [4096,1024]
    u16* Wqkvt = Xb + (size_t)BS * H;        // [3072,1024] (N-permuted, see prep)
    u16* Wot   = Wqkvt + (size_t)N3 * H;     // [1024,1024]
    u16* Qb    = Wot + (size_t)H * H;        // [bh][s][d]
    u16* Kb    = Qb + SH;
    u16* Vtb   = Kb + SH;                    // [bh][d][s] (written transposed)
    u16* AOb   = Vtb + SH;                   // [4096,1024] bf16
    float* cosT = (float*)(AOb + (size_t)BS * H);   // [2048][32]
    float* sinT = cosT + 2048 * 32;

    prep<<<8448, 256, 0, stream>>>(hs, Xb, Wqkv, Wqkvt, Wo, Wot, cosT, sinT);

    gemm_qkv<<<192, 512, 0, stream>>>(Xb, Wqkvt, cosT, sinT, Qb, Kb, Vtb);

    attn_kernel<<<dim3(8, 32), 256, 0, stream>>>(Qb, Kb, Vtb, AOb);

    gemm_out<<<dim3(H / 128, BS / 128), 256, 0, stream>>>(AOb, Wot, out);
}

// Round 8
// 190.809 us; speedup vs baseline: 1.1049x; 1.1049x over previous
//
#include <hip/hip_runtime.h>
#include <hip/hip_bf16.h>

typedef __bf16 bf16x8 __attribute__((ext_vector_type(8)));
typedef float f32x4 __attribute__((ext_vector_type(4)));
typedef unsigned short u16;

__device__ __forceinline__ u16 f2bf(float f) {
    union { float f; unsigned u; } x{f};
    unsigned r = x.u + 0x7fffu + ((x.u >> 16) & 1u);
    return (u16)(r >> 16);
}
// fast round-half-up pack of two fp32 -> packed bf16x2 (P >= 0, never NaN/Inf)
__device__ __forceinline__ unsigned pk2(float a, float b) {
    union { float f; unsigned u; } x{a}, y{b};
    return ((x.u + 0x8000u) >> 16) | ((y.u + 0x8000u) & 0xffff0000u);
}
// hardware exp2 (v_exp_f32); avoids glibc __exp2f macro collision
__device__ __forceinline__ float ex2(float x) { return __builtin_amdgcn_exp2f(x); }
__device__ __forceinline__ f32x4 zero4() { f32x4 z = {0.f, 0.f, 0.f, 0.f}; return z; }

// async global->LDS, 16B per lane; HW writes lane i at ldsbase + i*16
typedef const __attribute__((address_space(1))) unsigned int* gp1_t;
typedef __attribute__((address_space(3))) unsigned int* lp3_t;
__device__ __forceinline__ void async16(const u16* g, u16* l) {
    __builtin_amdgcn_global_load_lds((gp1_t)g, (lp3_t)l, 16, 0, 0);
}

// ======== prep: fused cast(hs->bf16) + W transposes + rope cos/sin tables ========
// blocks [0,4096): cast; [4096,7168): Wqkv^T (N-permuted for 8-phase gemm_qkv);
// [7168,8192): Wo^T; [8192,8448): tables
// Wqkvt perm (within each 256-col tile): orig (head hh, 16-frag f) -> position
// (f>>1)*8 + hh*2 + (f&1). Makes each gemm wave own one head with frag order
// f0,f1,f2,f3 at j=0..3 -> rope pairs (d, d+32) stay wave-local.
__global__ void __launch_bounds__(256) prep(const float* __restrict__ hs,
                                            u16* __restrict__ Xb,
                                            const float* __restrict__ Wqkv,
                                            u16* __restrict__ Wqkvt,
                                            const float* __restrict__ Wo,
                                            u16* __restrict__ Wot,
                                            float* __restrict__ cosT,
                                            float* __restrict__ sinT) {
    __shared__ float tile[32][33];
    const int blk = blockIdx.x, t = threadIdx.x;
    if (blk < 4096) {                       // cast 4096*1024 fp32 -> bf16
        int i = (blk * 256 + t) * 4;
        float4 v = *(const float4*)(hs + i);
        ushort4 o;
        o.x = f2bf(v.x); o.y = f2bf(v.y); o.z = f2bf(v.z); o.w = f2bf(v.w);
        *(ushort4*)(Xb + i) = o;
    } else if (blk < 8192) {                // transpose+cast W[K][N] -> Wt[N][K]
        const float* W; u16* Wt; int N, bx, by;
        bool qkv = (blk < 7168);
        if (qkv) { int bid = blk - 4096; W = Wqkv; Wt = Wqkvt; N = 3072; bx = bid % 96; by = bid / 96; }
        else     { int bid = blk - 7168; W = Wo;   Wt = Wot;   N = 1024; bx = bid % 32; by = bid / 32; }
        const int K = 1024;
        int tx = t & 31, ty = t >> 5;
        int n0 = bx * 32, k0 = by * 32;
#pragma unroll
        for (int i = 0; i < 32; i += 8)
            tile[ty + i][tx] = W[(size_t)(k0 + ty + i) * N + n0 + tx];
        __syncthreads();
#pragma unroll
        for (int i = 0; i < 32; i += 8) {
            int n = n0 + ty + i;
            int np = n;
            if (qkv) {
                int hh = (n >> 6) & 3, f = (n >> 4) & 3;
                np = (n & ~255) | (((f >> 1) * 8 + hh * 2 + (f & 1)) << 4) | (n & 15);
            }
            Wt[(size_t)np * K + k0 + tx] = f2bf(tile[tx][ty + i]);
        }
    } else {                                // rope tables: [2048][32] fp32
        int idx = (blk - 8192) * 256 + t;   // 65536
        int d = idx & 31, s = idx >> 5;
        float inv = expf(-(float)d * 0.374466538f);   // ln(160000)/32
        float th = (float)s * inv;
        cosT[idx] = cosf(th);
        sinT[idx] = sinf(th);
    }
}

// ======== 4-wave 128x128 GEMM K-loop (kept for gemm_out) ========
struct GemmCtx {
    f32x4 acc[4][4];
    int m16, q4, wm, wn;
};
template <int KDIM>
__device__ __forceinline__ void gemm_loop(const u16* __restrict__ A,
                                          const u16* __restrict__ Bt,
                                          int bm, int bn, GemmCtx& cx,
                                          u16* As, u16* Bs) {   // each [3][128*32]
    const int t = threadIdx.x;
    const int lane = t & 63, w = t >> 6;
    cx.wm = w >> 1; cx.wn = w & 1;
    cx.m16 = lane & 15; cx.q4 = lane >> 4;

    const int lrow = lane >> 2;
    const int kchunk = (lane & 3) ^ ((lane >> 3) & 3);   // swizzled global gather
    const u16* Ag = A + (size_t)(bm * 128 + w * 32 + lrow) * KDIM + kchunk * 8;
    const u16* Bg = Bt + (size_t)(bn * 128 + w * 32 + lrow) * KDIM + kchunk * 8;
    const int l0 = (w * 32) * 32;
    const int l1 = (w * 32 + 16) * 32;
    const int kswz = (cx.q4 ^ ((cx.m16 >> 1) & 3)) * 8;

#pragma unroll
    for (int i = 0; i < 4; i++)
#pragma unroll
        for (int j = 0; j < 4; j++) cx.acc[i][j] = zero4();

    constexpr int NT = KDIM / 32;
    // prologue: stage tiles 0,1 into buffers 0,1
    async16(Ag, As + l0);
    async16(Ag + 16 * KDIM, As + l1);
    async16(Bg, Bs + l0);
    async16(Bg + 16 * KDIM, Bs + l1);
    async16(Ag + 32, As + 4096 + l0);
    async16(Ag + 16 * KDIM + 32, As + 4096 + l1);
    async16(Bg + 32, Bs + 4096 + l0);
    async16(Bg + 16 * KDIM + 32, Bs + 4096 + l1);

    int co = 0, po = 2 * 4096;               // current / prefetch-dest buffer offsets
#pragma unroll 1
    for (int tt = 0; tt < NT; ++tt) {
        if (tt + 1 < NT) {
            asm volatile("s_waitcnt vmcnt(4)" ::: "memory");  // tile t landed
        } else {
            asm volatile("s_waitcnt vmcnt(0)" ::: "memory");
        }
        __builtin_amdgcn_s_barrier();
        __builtin_amdgcn_sched_barrier(0);
        if (tt + 2 < NT) {
            const int k0 = (tt + 2) * 32;
            async16(Ag + k0, As + po + l0);
            async16(Ag + 16 * KDIM + k0, As + po + l1);
            async16(Bg + k0, Bs + po + l0);
            async16(Bg + 16 * KDIM + k0, Bs + po + l1);
        }
        __builtin_amdgcn_sched_barrier(0);

        bf16x8 af[4], bf[4];
#pragma unroll
        for (int i = 0; i < 4; i++)
            af[i] = *(const bf16x8*)&As[co + (cx.wm * 64 + i * 16 + cx.m16) * 32 + kswz];
#pragma unroll
        for (int j = 0; j < 4; j++)
            bf[j] = *(const bf16x8*)&Bs[co + (cx.wn * 64 + j * 16 + cx.m16) * 32 + kswz];
#pragma unroll
        for (int i = 0; i < 4; i++)
#pragma unroll
            for (int j = 0; j < 4; j++)
                cx.acc[i][j] = __builtin_amdgcn_mfma_f32_16x16x32_bf16(af[i], bf[j], cx.acc[i][j], 0, 0, 0);

        asm volatile("" ::: "memory");
        __builtin_amdgcn_sched_barrier(0);
        co += 4096; if (co == 12288) co = 0;
        po += 4096; if (po == 12288) po = 0;
    }
}

// ======== gemm_qkv: 256^2, BK=64, 8 waves, 8-PHASE fine interleave (T2+T3+T4+T5) ====
// Each K-tile = 4 sub-phases {ds_read subtile || stage 1 half-tile -> barrier ->
// 16 MFMA (setprio) -> barrier}. A-frags live 2 phases, B-frags live whole tile ->
// LDS reads stay at 24/wave/tile. Stage schedule (into buf[T&1] / other buf):
// q0: A-high(T+1), q1: B-high(T+1), q2: A-low(T+2), q3: B-low(T+2) + vmcnt(4).
// Swizzle: LDS slot s of row r holds global k-chunk s ^ (r&7) (lane-local gather
// pre-swizzle); read slot = (ks*4+q4) ^ (m16&7) -> conflict-free (R4: conflicts=0).
__global__ void __launch_bounds__(512, 2) gemm_qkv(const u16* __restrict__ A,
                                                   const u16* __restrict__ Bt,
                                                   const float* __restrict__ cosT,
                                                   const float* __restrict__ sinT,
                                                   u16* __restrict__ Q,
                                                   u16* __restrict__ Kd,
                                                   u16* __restrict__ Vt) {
    __shared__ __align__(16) u16 As[2 * 256 * 64];
    __shared__ __align__(16) u16 Bs[2 * 256 * 64];
    constexpr int HB = 256 * 64;
    const int t = threadIdx.x, lane = t & 63, w = t >> 6;
    const int wm = w >> 2, wn = w & 3;
    const int m16 = lane & 15, q4 = lane >> 4, m7 = m16 & 7;
    const int hw = blockIdx.x;
    const int orig = (hw & 7) * 24 + (hw >> 3);   // bijective XCD swizzle: 192 = 8*24
    const int bm = orig / 12, bn = orig % 12;

    const int srow = lane >> 3;
    const int schunk = (lane & 7) ^ srow;
    const u16* Ag = A + (size_t)(bm * 256 + w * 8 + srow) * 1024 + schunk * 8;
    const u16* Bg = Bt + (size_t)(bn * 256 + w * 8 + srow) * 1024 + schunk * 8;
    u16* AsW = As + w * 512;     // wave's 8-row stage slab base
    u16* BsW = Bs + w * 512;

    f32x4 acc[8][4];
#pragma unroll
    for (int i = 0; i < 8; i++)
#pragma unroll
        for (int j = 0; j < 4; j++) acc[i][j] = zero4();

    const int slt0 = (q4 ^ m7) * 8;          // ks=0 read slot (u16 units)
    const int slt1 = ((4 + q4) ^ m7) * 8;    // ks=1

// stage one half-tile (2 async16/thread): half H of K-tile S, operand A/B
#define STGA(S, H) do { const u16* g_ = Ag + (size_t)(H) * 131072 + (S) * 64; \
    u16* l_ = AsW + ((S) & 1) * HB + (H) * 8192; \
    async16(g_, l_); async16(g_ + 65536, l_ + 4096); } while (0)
#define STGB(S, H) do { const u16* g_ = Bg + (size_t)(H) * 131072 + (S) * 64; \
    u16* l_ = BsW + ((S) & 1) * HB + (H) * 8192; \
    async16(g_, l_); async16(g_ + 65536, l_ + 4096); } while (0)

    // prologue: tile0 all 4 halves + tile1 A-low, B-low (12 loads/thread)
    STGA(0, 0); STGB(0, 0); STGA(0, 1); STGB(0, 1); STGA(1, 0); STGB(1, 0);
    asm volatile("s_waitcnt vmcnt(4)" ::: "memory");   // tile 0 landed
    __builtin_amdgcn_sched_barrier(0);
    __builtin_amdgcn_s_barrier();

#define MFMA8(IB, B0, B1) do { \
    _Pragma("unroll") for (int i4 = 0; i4 < 4; i4++) \
    _Pragma("unroll") for (int j2 = 0; j2 < 2; j2++) \
        acc[(IB) + i4][(JB) + j2] = __builtin_amdgcn_mfma_f32_16x16x32_bf16(a0[i4], B0[j2], acc[(IB) + i4][(JB) + j2], 0, 0, 0); \
    _Pragma("unroll") for (int i4 = 0; i4 < 4; i4++) \
    _Pragma("unroll") for (int j2 = 0; j2 < 2; j2++) \
        acc[(IB) + i4][(JB) + j2] = __builtin_amdgcn_mfma_f32_16x16x32_bf16(a1[i4], B1[j2], acc[(IB) + i4][(JB) + j2], 0, 0, 0); \
} while (0)

#define BAR1() do { __builtin_amdgcn_sched_barrier(0); __builtin_amdgcn_s_barrier(); \
                    __builtin_amdgcn_s_setprio(1); } while (0)
#define BAR2() do { __builtin_amdgcn_s_setprio(0); asm volatile("" ::: "memory"); \
                    __builtin_amdgcn_sched_barrier(0); __builtin_amdgcn_s_barrier(); } while (0)

#pragma unroll 1
    for (int T = 0; T < 16; ++T) {
        const int co = (T & 1) * HB;
        const int aL = co + (wm * 64 + m16) * 64;
        const int aH = aL + 128 * 64;
        const int bL = co + (wn * 32 + m16) * 64;
        const int bH = bL + 128 * 64;
        bf16x8 a0[4], a1[4], pl0[2], pl1[2], ph0[2], ph1[2];

        // ---- q0: read A-low + B-low; stage A-high(T+1); MFMA quad (lowA, lowB) ----
#pragma unroll
        for (int i4 = 0; i4 < 4; i4++) {
            a0[i4] = *(const bf16x8*)&As[aL + i4 * 1024 + slt0];
            a1[i4] = *(const bf16x8*)&As[aL + i4 * 1024 + slt1];
        }
#pragma unroll
        for (int j2 = 0; j2 < 2; j2++) {
            pl0[j2] = *(const bf16x8*)&Bs[bL + j2 * 1024 + slt0];
            pl1[j2] = *(const bf16x8*)&Bs[bL + j2 * 1024 + slt1];
        }
        if (T < 15) STGA(T + 1, 1);
        BAR1();
        { constexpr int JB = 0; MFMA8(0, pl0, pl1); }
        BAR2();

        // ---- q1: read B-high; stage B-high(T+1); MFMA (lowA, highB) reusing a0/a1 ----
#pragma unroll
        for (int j2 = 0; j2 < 2; j2++) {
            ph0[j2] = *(const bf16x8*)&Bs[bH + j2 * 1024 + slt0];
            ph1[j2] = *(const bf16x8*)&Bs[bH + j2 * 1024 + slt1];
        }
        if (T < 15) STGB(T + 1, 1);
        BAR1();
        { constexpr int JB = 2; MFMA8(0, ph0, ph1); }
        BAR2();

        // ---- q2: reload A-high; stage A-low(T+2); MFMA (highA, lowB) reusing pl ----
#pragma unroll
        for (int i4 = 0; i4 < 4; i4++) {
            a0[i4] = *(const bf16x8*)&As[aH + i4 * 1024 + slt0];
            a1[i4] = *(const bf16x8*)&As[aH + i4 * 1024 + slt1];
        }
        if (T < 14) STGA(T + 2, 0);
        BAR1();
        { constexpr int JB = 0; MFMA8(4, pl0, pl1); }
        BAR2();

        // ---- q3: no reads; stage B-low(T+2) + vmcnt; MFMA (highA, highB) ----
        if (T < 14) {
            STGB(T + 2, 0);
            asm volatile("s_waitcnt vmcnt(4)" ::: "memory");  // tile T+1 landed
        } else {
            asm volatile("s_waitcnt vmcnt(0)" ::: "memory");
        }
        BAR1();
        { constexpr int JB = 2; MFMA8(4, ph0, ph1); }
        BAR2();
    }
#undef STGA
#undef STGB
#undef MFMA8
#undef BAR1
#undef BAR2

    // ==== epilogue: wave = one (type, head) via virtual colbase (perm baked in W) ====
    const int colbase = bn * 256 + wn * 64;
    const int type = colbase >> 10;            // 0=Q 1=K 2=V
    const int h = (colbase & 1023) >> 6;

    if (type == 2) {
        // V transposed: Vt[bh][d][s]; lane's rr=0..3 are 4 consecutive s -> 8B store
#pragma unroll
        for (int i = 0; i < 8; i++) {
            int sr = bm * 256 + (i >> 2) * 128 + wm * 64 + (i & 3) * 16 + q4 * 4;
            int b = sr >> 11, sl = sr & 2047;
            size_t ob = (size_t)(b * 16 + h) * 64 * 2048;
#pragma unroll
            for (int j = 0; j < 4; j++) {
                int d = j * 16 + m16;
                ushort4 o;
                o.x = f2bf(acc[i][j][0]);
                o.y = f2bf(acc[i][j][1]);
                o.z = f2bf(acc[i][j][2]);
                o.w = f2bf(acc[i][j][3]);
                *(ushort4*)&Vt[ob + (size_t)d * 2048 + sl] = o;
            }
        }
    } else {
        u16* dst = (type == 0) ? Q : Kd;
        const float qs = (type == 0) ? 0.1803368801f /*0.125*log2(e)*/ : 1.0f;
#pragma unroll
        for (int i = 0; i < 8; i++)
#pragma unroll
            for (int rr = 0; rr < 4; rr++) {
                int r = bm * 256 + (i >> 2) * 128 + wm * 64 + (i & 3) * 16 + q4 * 4 + rr;
                int b = r >> 11, s = r & 2047;
                size_t ob = ((size_t)((b * 16 + h) * 2048 + s)) * 64;
#pragma unroll
                for (int j2 = 0; j2 < 2; j2++) {
                    int d = j2 * 16 + m16;                 // d in [0,32)
                    float cs = cosT[s * 32 + d];
                    float sn = sinT[s * 32 + d];
                    float x1 = acc[i][j2][rr];
                    float x2 = acc[i][j2 + 2][rr];
                    dst[ob + d]      = f2bf((x1 * cs - x2 * sn) * qs);
                    dst[ob + d + 32] = f2bf((x2 * cs + x1 * sn) * qs);
                }
            }
    }
}

// ---------------- out-proj GEMM: C[M,N] fp32 = A[M,K] @ Bt[N,K]^T ----------------
__global__ void __launch_bounds__(256) gemm_out(const u16* __restrict__ A,
                                                const u16* __restrict__ Bt,
                                                float* __restrict__ C) {
    __shared__ __align__(16) u16 As[3 * 128 * 32];
    __shared__ __align__(16) u16 Bs[3 * 128 * 32];
    GemmCtx cx;
    const int bm = blockIdx.y, bn = blockIdx.x;
    gemm_loop<1024>(A, Bt, bm, bn, cx, As, Bs);
    const int N = 1024;
#pragma unroll
    for (int i = 0; i < 4; i++)
#pragma unroll
        for (int j = 0; j < 4; j++)
#pragma unroll
            for (int rr = 0; rr < 4; rr++) {
                int row = bm * 128 + cx.wm * 64 + i * 16 + cx.q4 * 4 + rr;
                int col = bn * 128 + cx.wn * 64 + j * 16 + cx.m16;
                C[(size_t)row * N + col] = cx.acc[i][j][rr];
            }
}

// ---------------- causal flash attention (R5 v1 + T5 setprio): 512 thr, 8 waves ----
// grid (8, B*nh): block bx handles supertile pair {bx, 15-bx} -> exactly 34 K-tiles
// per block. Each wave owns one 16-q-row group; per-thread staging is 16B K + 16B V
// per tile. Waves whose diagonal tile jd = 2*st + (w>=4) has passed skip compute but
// keep barriers. S^T = mfma(K_frag, Q_frag); fixed exponent offset M=24.
// setprio(1) wraps the MFMA clusters (m191: +4-7% on this structure type).
__global__ void __launch_bounds__(512) attn_kernel(const u16* __restrict__ Q,
                                                   const u16* __restrict__ Kg_,
                                                   const u16* __restrict__ Vtg_,
                                                   u16* __restrict__ O) {
    __shared__ __align__(16) u16 Ks[2][64][72];     // [buf][key][d]
    __shared__ __align__(16) u16 Vs[2][64][72];     // [buf][d][key]
    __shared__ __align__(16) u16 Pt[8][16][72];     // [wave][q][key]
    const int t = threadIdx.x, w = t >> 6;
    const int m16 = t & 15, q4 = (t & 63) >> 4;
    const int bx = blockIdx.x, bh = blockIdx.y;
    const size_t base = (size_t)bh * 2048 * 64;
    const int b = bh >> 4, h = bh & 15;
    const int skey = t >> 3, sc = (t & 7) * 8;      // 16B staging per thread

#pragma unroll 1
    for (int ph = 0; ph < 2; ph++) {
        const int st = ph ? (15 - bx) : bx;
        const int qrow = st * 128 + w * 16 + m16;
        const u16* Qg = Q + base + (size_t)qrow * 64;
        bf16x8 qf0 = *(const bf16x8*)(Qg + q4 * 8);
        bf16x8 qf1 = *(const bf16x8*)(Qg + 32 + q4 * 8);

        f32x4 occ[4];
#pragma unroll
        for (int dc = 0; dc < 4; dc++) occ[dc] = zero4();
        float li = 0.f;

        const int jtmax = 2 * st + 1;
        const int jd = 2 * st + (w >> 2);   // this wave's diagonal tile

        const u16* Kb0 = Kg_ + base + skey * 64 + sc;            // + jt*4096
        const u16* Vt0 = Vtg_ + base + (size_t)skey * 2048 + sc; // + jt*64
        uint4 ka = *(const uint4*)(Kb0);
        uint4 va = *(const uint4*)(Vt0);

#pragma unroll 1
        for (int jt = 0; jt <= jtmax; jt++) {
            const int bi = jt & 1;
            *(uint4*)&Ks[bi][skey][sc] = ka;
            *(uint4*)&Vs[bi][skey][sc] = va;
            if (jt < jtmax) {
                ka = *(const uint4*)(Kb0 + (size_t)(jt + 1) * 4096);
                va = *(const uint4*)(Vt0 + (size_t)(jt + 1) * 64);
            }
            __syncthreads();   // single barrier per tile

            if (jt <= jd) {    // wave-uniform activity
                // S^T = K @ Q^T : col(m16)=q, key = c*16 + q4*4 + rr (log2 domain)
                f32x4 stv[4];
#pragma unroll
                for (int c = 0; c < 4; c++) stv[c] = zero4();
                __builtin_amdgcn_s_setprio(1);
#pragma unroll
                for (int c = 0; c < 4; c++) {
                    bf16x8 kf0 = *(const bf16x8*)&Ks[bi][c * 16 + m16][q4 * 8];
                    bf16x8 kf1 = *(const bf16x8*)&Ks[bi][c * 16 + m16][32 + q4 * 8];
                    stv[c] = __builtin_amdgcn_mfma_f32_16x16x32_bf16(kf0, qf0, stv[c], 0, 0, 0);
                    stv[c] = __builtin_amdgcn_mfma_f32_16x16x32_bf16(kf1, qf1, stv[c], 0, 0, 0);
                }
                __builtin_amdgcn_s_setprio(0);

                float pv[4][4];
#pragma unroll
                for (int c = 0; c < 4; c++)
#pragma unroll
                    for (int rr = 0; rr < 4; rr++) pv[c][rr] = stv[c][rr];
                if (jt == jd) {   // diagonal: mask key > q (lane-local q)
                    const int ql = qrow - 64 * jt;
#pragma unroll
                    for (int c = 0; c < 4; c++)
#pragma unroll
                        for (int rr = 0; rr < 4; rr++)
                            if (c * 16 + q4 * 4 + rr > ql) pv[c][rr] = -1e30f;
                }

                // fixed-max softmax: p = 2^(s' - 24)
#pragma unroll
                for (int c = 0; c < 4; c++) {
                    float p0 = ex2(pv[c][0] - 24.f);
                    float p1 = ex2(pv[c][1] - 24.f);
                    float p2 = ex2(pv[c][2] - 24.f);
                    float p3 = ex2(pv[c][3] - 24.f);
                    li += (p0 + p1) + (p2 + p3);
                    *(uint2*)&Pt[w][m16][c * 16 + q4 * 4] = make_uint2(pk2(p0, p1), pk2(p2, p3));
                }

                // O^T += V^T @ P^T
                __builtin_amdgcn_s_setprio(1);
#pragma unroll
                for (int ks = 0; ks < 2; ks++) {
                    bf16x8 pf = *(const bf16x8*)&Pt[w][m16][ks * 32 + q4 * 8];
#pragma unroll
                    for (int dc = 0; dc < 4; dc++) {
                        bf16x8 vf = *(const bf16x8*)&Vs[bi][dc * 16 + m16][ks * 32 + q4 * 8];
                        occ[dc] = __builtin_amdgcn_mfma_f32_16x16x32_bf16(vf, pf, occ[dc], 0, 0, 0);
                    }
                }
                __builtin_amdgcn_s_setprio(0);
            }
        }

        // epilogue: lane owns q-row qrow; d = dc*16 + q4*4 + rr
        li += __shfl_xor(li, 16);
        li += __shfl_xor(li, 32);
        float rli = 1.0f / li;
        u16* Op = O + ((size_t)(b * 2048 + qrow)) * 1024 + h * 64 + q4 * 4;
#pragma unroll
        for (int dc = 0; dc < 4; dc++) {
            ushort4 o;
            o.x = f2bf(occ[dc][0] * rli);
            o.y = f2bf(occ[dc][1] * rli);
            o.z = f2bf(occ[dc][2] * rli);
            o.w = f2bf(occ[dc][3] * rli);
            *(ushort4*)(Op + dc * 16) = o;
        }
        __syncthreads();  // protect LDS buffers across the phase boundary
    }
}

extern "C" void kernel_launch(void* const* d_in, const int* in_sizes, int n_in,
                              void* d_out, int out_size, void* d_ws, size_t ws_size,
                              hipStream_t stream) {
    const float* hs   = (const float*)d_in[0];
    const float* Wqkv = (const float*)d_in[2];
    const float* Wo   = (const float*)d_in[3];
    float* out = (float*)d_out;

    const int BS = 4096;
    const int H = 1024, N3 = 3072;
    const int SH = 32 * 2048 * 64;

    u16* Xb    = (u16*)d_ws;                 // [4096,1024]
    u16* Wqkvt = Xb + (size_t)BS * H;        // [3072,1024] (N-permuted, see prep)
    u16* Wot   = Wqkvt + (size_t)N3 * H;     // [1024,1024]
    u16* Qb    = Wot + (size_t)H * H;        // [bh][s][d]
    u16* Kb    = Qb + SH;
    u16* Vtb   = Kb + SH;                    // [bh][d][s] (written transposed)
    u16* AOb   = Vtb + SH;                   // [4096,1024] bf16
    float* cosT = (float*)(AOb + (size_t)BS * H);   // [2048][32]
    float* sinT = cosT + 2048 * 32;

    prep<<<8448, 256, 0, stream>>>(hs, Xb, Wqkv, Wqkvt, Wo, Wot, cosT, sinT);

    gemm_qkv<<<192, 512, 0, stream>>>(Xb, Wqkvt, cosT, sinT, Qb, Kb, Vtb);

    attn_kernel<<<dim3(8, 32), 512, 0, stream>>>(Qb, Kb, Vtb, AOb);

    gemm_out<<<dim3(H / 128, BS / 128), 256, 0, stream>>>(AOb, Wot, out);
}

// Round 9
// 188.731 us; speedup vs baseline: 1.1170x; 1.0110x over previous
//
#include <hip/hip_runtime.h>
#include <hip/hip_bf16.h>

typedef __bf16 bf16x8 __attribute__((ext_vector_type(8)));
typedef float f32x4 __attribute__((ext_vector_type(4)));
typedef unsigned short u16;

__device__ __forceinline__ u16 f2bf(float f) {
    union { float f; unsigned u; } x{f};
    unsigned r = x.u + 0x7fffu + ((x.u >> 16) & 1u);
    return (u16)(r >> 16);
}
// fast round-half-up pack of two fp32 -> packed bf16x2 (P >= 0, never NaN/Inf)
__device__ __forceinline__ unsigned pk2(float a, float b) {
    union { float f; unsigned u; } x{a}, y{b};
    return ((x.u + 0x8000u) >> 16) | ((y.u + 0x8000u) & 0xffff0000u);
}
// hardware exp2 (v_exp_f32); avoids glibc __exp2f macro collision
__device__ __forceinline__ float ex2(float x) { return __builtin_amdgcn_exp2f(x); }
__device__ __forceinline__ f32x4 zero4() { f32x4 z = {0.f, 0.f, 0.f, 0.f}; return z; }

// async global->LDS, 16B per lane; HW writes lane i at ldsbase + i*16
typedef const __attribute__((address_space(1))) unsigned int* gp1_t;
typedef __attribute__((address_space(3))) unsigned int* lp3_t;
__device__ __forceinline__ void async16(const u16* g, u16* l) {
    __builtin_amdgcn_global_load_lds((gp1_t)g, (lp3_t)l, 16, 0, 0);
}

// ======== prep: fused cast(hs->bf16) + W transposes + rope cos/sin tables ========
// blocks [0,4096): cast; [4096,7168): Wqkv^T (N-permuted for 8-phase gemm_qkv);
// [7168,8192): Wo^T; [8192,8448): tables
// Wqkvt perm (within each 256-col tile): orig (head hh, 16-frag f) -> position
// (f>>1)*8 + hh*2 + (f&1). Makes each gemm wave own one head with frag order
// f0,f1,f2,f3 at j=0..3 -> rope pairs (d, d+32) stay wave-local.
__global__ void __launch_bounds__(256) prep(const float* __restrict__ hs,
                                            u16* __restrict__ Xb,
                                            const float* __restrict__ Wqkv,
                                            u16* __restrict__ Wqkvt,
                                            const float* __restrict__ Wo,
                                            u16* __restrict__ Wot,
                                            float* __restrict__ cosT,
                                            float* __restrict__ sinT) {
    __shared__ float tile[32][33];
    const int blk = blockIdx.x, t = threadIdx.x;
    if (blk < 4096) {                       // cast 4096*1024 fp32 -> bf16
        int i = (blk * 256 + t) * 4;
        float4 v = *(const float4*)(hs + i);
        ushort4 o;
        o.x = f2bf(v.x); o.y = f2bf(v.y); o.z = f2bf(v.z); o.w = f2bf(v.w);
        *(ushort4*)(Xb + i) = o;
    } else if (blk < 8192) {                // transpose+cast W[K][N] -> Wt[N][K]
        const float* W; u16* Wt; int N, bx, by;
        bool qkv = (blk < 7168);
        if (qkv) { int bid = blk - 4096; W = Wqkv; Wt = Wqkvt; N = 3072; bx = bid % 96; by = bid / 96; }
        else     { int bid = blk - 7168; W = Wo;   Wt = Wot;   N = 1024; bx = bid % 32; by = bid / 32; }
        const int K = 1024;
        int tx = t & 31, ty = t >> 5;
        int n0 = bx * 32, k0 = by * 32;
#pragma unroll
        for (int i = 0; i < 32; i += 8)
            tile[ty + i][tx] = W[(size_t)(k0 + ty + i) * N + n0 + tx];
        __syncthreads();
#pragma unroll
        for (int i = 0; i < 32; i += 8) {
            int n = n0 + ty + i;
            int np = n;
            if (qkv) {
                int hh = (n >> 6) & 3, f = (n >> 4) & 3;
                np = (n & ~255) | (((f >> 1) * 8 + hh * 2 + (f & 1)) << 4) | (n & 15);
            }
            Wt[(size_t)np * K + k0 + tx] = f2bf(tile[tx][ty + i]);
        }
    } else {                                // rope tables: [2048][32] fp32
        int idx = (blk - 8192) * 256 + t;   // 65536
        int d = idx & 31, s = idx >> 5;
        float inv = expf(-(float)d * 0.374466538f);   // ln(160000)/32
        float th = (float)s * inv;
        cosT[idx] = cosf(th);
        sinT[idx] = sinf(th);
    }
}

// ======== 4-wave 128x128 GEMM K-loop (kept for gemm_out) ========
struct GemmCtx {
    f32x4 acc[4][4];
    int m16, q4, wm, wn;
};
template <int KDIM>
__device__ __forceinline__ void gemm_loop(const u16* __restrict__ A,
                                          const u16* __restrict__ Bt,
                                          int bm, int bn, GemmCtx& cx,
                                          u16* As, u16* Bs) {   // each [3][128*32]
    const int t = threadIdx.x;
    const int lane = t & 63, w = t >> 6;
    cx.wm = w >> 1; cx.wn = w & 1;
    cx.m16 = lane & 15; cx.q4 = lane >> 4;

    const int lrow = lane >> 2;
    const int kchunk = (lane & 3) ^ ((lane >> 3) & 3);   // swizzled global gather
    const u16* Ag = A + (size_t)(bm * 128 + w * 32 + lrow) * KDIM + kchunk * 8;
    const u16* Bg = Bt + (size_t)(bn * 128 + w * 32 + lrow) * KDIM + kchunk * 8;
    const int l0 = (w * 32) * 32;
    const int l1 = (w * 32 + 16) * 32;
    const int kswz = (cx.q4 ^ ((cx.m16 >> 1) & 3)) * 8;

#pragma unroll
    for (int i = 0; i < 4; i++)
#pragma unroll
        for (int j = 0; j < 4; j++) cx.acc[i][j] = zero4();

    constexpr int NT = KDIM / 32;
    // prologue: stage tiles 0,1 into buffers 0,1
    async16(Ag, As + l0);
    async16(Ag + 16 * KDIM, As + l1);
    async16(Bg, Bs + l0);
    async16(Bg + 16 * KDIM, Bs + l1);
    async16(Ag + 32, As + 4096 + l0);
    async16(Ag + 16 * KDIM + 32, As + 4096 + l1);
    async16(Bg + 32, Bs + 4096 + l0);
    async16(Bg + 16 * KDIM + 32, Bs + 4096 + l1);

    int co = 0, po = 2 * 4096;               // current / prefetch-dest buffer offsets
#pragma unroll 1
    for (int tt = 0; tt < NT; ++tt) {
        if (tt + 1 < NT) {
            asm volatile("s_waitcnt vmcnt(4)" ::: "memory");  // tile t landed
        } else {
            asm volatile("s_waitcnt vmcnt(0)" ::: "memory");
        }
        __builtin_amdgcn_s_barrier();
        __builtin_amdgcn_sched_barrier(0);
        if (tt + 2 < NT) {
            const int k0 = (tt + 2) * 32;
            async16(Ag + k0, As + po + l0);
            async16(Ag + 16 * KDIM + k0, As + po + l1);
            async16(Bg + k0, Bs + po + l0);
            async16(Bg + 16 * KDIM + k0, Bs + po + l1);
        }
        __builtin_amdgcn_sched_barrier(0);

        bf16x8 af[4], bf[4];
#pragma unroll
        for (int i = 0; i < 4; i++)
            af[i] = *(const bf16x8*)&As[co + (cx.wm * 64 + i * 16 + cx.m16) * 32 + kswz];
#pragma unroll
        for (int j = 0; j < 4; j++)
            bf[j] = *(const bf16x8*)&Bs[co + (cx.wn * 64 + j * 16 + cx.m16) * 32 + kswz];
#pragma unroll
        for (int i = 0; i < 4; i++)
#pragma unroll
            for (int j = 0; j < 4; j++)
                cx.acc[i][j] = __builtin_amdgcn_mfma_f32_16x16x32_bf16(af[i], bf[j], cx.acc[i][j], 0, 0, 0);

        asm volatile("" ::: "memory");
        __builtin_amdgcn_sched_barrier(0);
        co += 4096; if (co == 12288) co = 0;
        po += 4096; if (po == 12288) po = 0;
    }
}

// ======== gemm_qkv: 256^2, BK=64, 8 waves, 8-PHASE fine interleave (T2+T3+T4+T5) ====
// Each K-tile = 4 sub-phases {ds_read subtile || stage 1 half-tile -> barrier ->
// 16 MFMA (setprio) -> barrier}. A-frags live 2 phases, B-frags live whole tile ->
// LDS reads stay at 24/wave/tile. Stage schedule (into buf[T&1] / other buf):
// q0: A-high(T+1), q1: B-high(T+1), q2: A-low(T+2), q3: B-low(T+2) + vmcnt(4).
// Swizzle: LDS slot s of row r holds global k-chunk s ^ (r&7) (lane-local gather
// pre-swizzle); read slot = (ks*4+q4) ^ (m16&7) -> conflict-free (R4: conflicts=0).
__global__ void __launch_bounds__(512, 2) gemm_qkv(const u16* __restrict__ A,
                                                   const u16* __restrict__ Bt,
                                                   const float* __restrict__ cosT,
                                                   const float* __restrict__ sinT,
                                                   u16* __restrict__ Q,
                                                   u16* __restrict__ Kd,
                                                   u16* __restrict__ Vt) {
    __shared__ __align__(16) u16 As[2 * 256 * 64];
    __shared__ __align__(16) u16 Bs[2 * 256 * 64];
    constexpr int HB = 256 * 64;
    const int t = threadIdx.x, lane = t & 63, w = t >> 6;
    const int wm = w >> 2, wn = w & 3;
    const int m16 = lane & 15, q4 = lane >> 4, m7 = m16 & 7;
    const int hw = blockIdx.x;
    const int orig = (hw & 7) * 24 + (hw >> 3);   // bijective XCD swizzle: 192 = 8*24
    const int bm = orig / 12, bn = orig % 12;

    const int srow = lane >> 3;
    const int schunk = (lane & 7) ^ srow;
    const u16* Ag = A + (size_t)(bm * 256 + w * 8 + srow) * 1024 + schunk * 8;
    const u16* Bg = Bt + (size_t)(bn * 256 + w * 8 + srow) * 1024 + schunk * 8;
    u16* AsW = As + w * 512;     // wave's 8-row stage slab base
    u16* BsW = Bs + w * 512;

    f32x4 acc[8][4];
#pragma unroll
    for (int i = 0; i < 8; i++)
#pragma unroll
        for (int j = 0; j < 4; j++) acc[i][j] = zero4();

    const int slt0 = (q4 ^ m7) * 8;          // ks=0 read slot (u16 units)
    const int slt1 = ((4 + q4) ^ m7) * 8;    // ks=1

// stage one half-tile (2 async16/thread): half H of K-tile S, operand A/B
#define STGA(S, H) do { const u16* g_ = Ag + (size_t)(H) * 131072 + (S) * 64; \
    u16* l_ = AsW + ((S) & 1) * HB + (H) * 8192; \
    async16(g_, l_); async16(g_ + 65536, l_ + 4096); } while (0)
#define STGB(S, H) do { const u16* g_ = Bg + (size_t)(H) * 131072 + (S) * 64; \
    u16* l_ = BsW + ((S) & 1) * HB + (H) * 8192; \
    async16(g_, l_); async16(g_ + 65536, l_ + 4096); } while (0)

    // prologue: tile0 all 4 halves + tile1 A-low, B-low (12 loads/thread)
    STGA(0, 0); STGB(0, 0); STGA(0, 1); STGB(0, 1); STGA(1, 0); STGB(1, 0);
    asm volatile("s_waitcnt vmcnt(4)" ::: "memory");   // tile 0 landed
    __builtin_amdgcn_sched_barrier(0);
    __builtin_amdgcn_s_barrier();

#define MFMA8(IB, B0, B1) do { \
    _Pragma("unroll") for (int i4 = 0; i4 < 4; i4++) \
    _Pragma("unroll") for (int j2 = 0; j2 < 2; j2++) \
        acc[(IB) + i4][(JB) + j2] = __builtin_amdgcn_mfma_f32_16x16x32_bf16(a0[i4], B0[j2], acc[(IB) + i4][(JB) + j2], 0, 0, 0); \
    _Pragma("unroll") for (int i4 = 0; i4 < 4; i4++) \
    _Pragma("unroll") for (int j2 = 0; j2 < 2; j2++) \
        acc[(IB) + i4][(JB) + j2] = __builtin_amdgcn_mfma_f32_16x16x32_bf16(a1[i4], B1[j2], acc[(IB) + i4][(JB) + j2], 0, 0, 0); \
} while (0)

#define BAR1() do { __builtin_amdgcn_sched_barrier(0); __builtin_amdgcn_s_barrier(); \
                    __builtin_amdgcn_s_setprio(1); } while (0)
#define BAR2() do { __builtin_amdgcn_s_setprio(0); asm volatile("" ::: "memory"); \
                    __builtin_amdgcn_sched_barrier(0); __builtin_amdgcn_s_barrier(); } while (0)

#pragma unroll 1
    for (int T = 0; T < 16; ++T) {
        const int co = (T & 1) * HB;
        const int aL = co + (wm * 64 + m16) * 64;
        const int aH = aL + 128 * 64;
        const int bL = co + (wn * 32 + m16) * 64;
        const int bH = bL + 128 * 64;
        bf16x8 a0[4], a1[4], pl0[2], pl1[2], ph0[2], ph1[2];

        // ---- q0: read A-low + B-low; stage A-high(T+1); MFMA quad (lowA, lowB) ----
#pragma unroll
        for (int i4 = 0; i4 < 4; i4++) {
            a0[i4] = *(const bf16x8*)&As[aL + i4 * 1024 + slt0];
            a1[i4] = *(const bf16x8*)&As[aL + i4 * 1024 + slt1];
        }
#pragma unroll
        for (int j2 = 0; j2 < 2; j2++) {
            pl0[j2] = *(const bf16x8*)&Bs[bL + j2 * 1024 + slt0];
            pl1[j2] = *(const bf16x8*)&Bs[bL + j2 * 1024 + slt1];
        }
        if (T < 15) STGA(T + 1, 1);
        BAR1();
        { constexpr int JB = 0; MFMA8(0, pl0, pl1); }
        BAR2();

        // ---- q1: read B-high; stage B-high(T+1); MFMA (lowA, highB) reusing a0/a1 ----
#pragma unroll
        for (int j2 = 0; j2 < 2; j2++) {
            ph0[j2] = *(const bf16x8*)&Bs[bH + j2 * 1024 + slt0];
            ph1[j2] = *(const bf16x8*)&Bs[bH + j2 * 1024 + slt1];
        }
        if (T < 15) STGB(T + 1, 1);
        BAR1();
        { constexpr int JB = 2; MFMA8(0, ph0, ph1); }
        BAR2();

        // ---- q2: reload A-high; stage A-low(T+2); MFMA (highA, lowB) reusing pl ----
#pragma unroll
        for (int i4 = 0; i4 < 4; i4++) {
            a0[i4] = *(const bf16x8*)&As[aH + i4 * 1024 + slt0];
            a1[i4] = *(const bf16x8*)&As[aH + i4 * 1024 + slt1];
        }
        if (T < 14) STGA(T + 2, 0);
        BAR1();
        { constexpr int JB = 0; MFMA8(4, pl0, pl1); }
        BAR2();

        // ---- q3: no reads; stage B-low(T+2) + vmcnt; MFMA (highA, highB) ----
        if (T < 14) {
            STGB(T + 2, 0);
            asm volatile("s_waitcnt vmcnt(4)" ::: "memory");  // tile T+1 landed
        } else {
            asm volatile("s_waitcnt vmcnt(0)" ::: "memory");
        }
        BAR1();
        { constexpr int JB = 2; MFMA8(4, ph0, ph1); }
        BAR2();
    }
#undef STGA
#undef STGB
#undef MFMA8
#undef BAR1
#undef BAR2

    // ==== epilogue: wave = one (type, head) via virtual colbase (perm baked in W) ====
    const int colbase = bn * 256 + wn * 64;
    const int type = colbase >> 10;            // 0=Q 1=K 2=V
    const int h = (colbase & 1023) >> 6;

    if (type == 2) {
        // V transposed: Vt[bh][d][s]; lane's rr=0..3 are 4 consecutive s -> 8B store
#pragma unroll
        for (int i = 0; i < 8; i++) {
            int sr = bm * 256 + (i >> 2) * 128 + wm * 64 + (i & 3) * 16 + q4 * 4;
            int b = sr >> 11, sl = sr & 2047;
            size_t ob = (size_t)(b * 16 + h) * 64 * 2048;
#pragma unroll
            for (int j = 0; j < 4; j++) {
                int d = j * 16 + m16;
                ushort4 o;
                o.x = f2bf(acc[i][j][0]);
                o.y = f2bf(acc[i][j][1]);
                o.z = f2bf(acc[i][j][2]);
                o.w = f2bf(acc[i][j][3]);
                *(ushort4*)&Vt[ob + (size_t)d * 2048 + sl] = o;
            }
        }
    } else {
        u16* dst = (type == 0) ? Q : Kd;
        const float qs = (type == 0) ? 0.1803368801f /*0.125*log2(e)*/ : 1.0f;
#pragma unroll
        for (int i = 0; i < 8; i++)
#pragma unroll
            for (int rr = 0; rr < 4; rr++) {
                int r = bm * 256 + (i >> 2) * 128 + wm * 64 + (i & 3) * 16 + q4 * 4 + rr;
                int b = r >> 11, s = r & 2047;
                size_t ob = ((size_t)((b * 16 + h) * 2048 + s)) * 64;
#pragma unroll
                for (int j2 = 0; j2 < 2; j2++) {
                    int d = j2 * 16 + m16;                 // d in [0,32)
                    float cs = cosT[s * 32 + d];
                    float sn = sinT[s * 32 + d];
                    float x1 = acc[i][j2][rr];
                    float x2 = acc[i][j2 + 2][rr];
                    dst[ob + d]      = f2bf((x1 * cs - x2 * sn) * qs);
                    dst[ob + d + 32] = f2bf((x2 * cs + x1 * sn) * qs);
                }
            }
    }
}

// ---------------- out-proj GEMM: C[M,N] fp32 = A[M,K] @ Bt[N,K]^T ----------------
// 1D grid 256, chunked XCD swizzle (256 = 8*32): each XCD gets 4 bm-panels (1MB)
// + full Bt (2MB) -> 3MB L2-resident, Bt/A fetched once per XCD.
__global__ void __launch_bounds__(256) gemm_out(const u16* __restrict__ A,
                                                const u16* __restrict__ Bt,
                                                float* __restrict__ C) {
    __shared__ __align__(16) u16 As[3 * 128 * 32];
    __shared__ __align__(16) u16 Bs[3 * 128 * 32];
    GemmCtx cx;
    const int hw = blockIdx.x;
    const int orig = (hw & 7) * 32 + (hw >> 3);   // bijective: 256 % 8 == 0
    const int bm = orig >> 3, bn = orig & 7;
    gemm_loop<1024>(A, Bt, bm, bn, cx, As, Bs);
    const int N = 1024;
#pragma unroll
    for (int i = 0; i < 4; i++)
#pragma unroll
        for (int j = 0; j < 4; j++)
#pragma unroll
            for (int rr = 0; rr < 4; rr++) {
                int row = bm * 128 + cx.wm * 64 + i * 16 + cx.q4 * 4 + rr;
                int col = bn * 128 + cx.wn * 64 + j * 16 + cx.m16;
                C[(size_t)row * N + col] = cx.acc[i][j][rr];
            }
}

// ---------------- causal flash attention (R5 v1 + XCD-local bh mapping) ----------------
// 1D grid 256; bid = (bh%8) + 8*bx + 64*(bh/8)  =>  all 8 bx-blocks of one head land
// on ONE XCD (assuming round-robin id%8 placement): that head's K/V (512KB) is
// fetched once into that XCD's L2 and shared by its 8 blocks (4 heads/XCD = 2MB).
// Block bx handles supertile pair {bx, 15-bx} -> exactly 34 K-tiles per block.
// Each wave owns one 16-q-row group; per-thread staging is 16B K + 16B V per tile.
// Waves whose diagonal tile jd = 2*st + (w>=4) has passed skip compute but keep
// barriers. S^T = mfma(K_frag, Q_frag); fixed exponent offset M=24; 1 barrier/tile.
__global__ void __launch_bounds__(512) attn_kernel(const u16* __restrict__ Q,
                                                   const u16* __restrict__ Kg_,
                                                   const u16* __restrict__ Vtg_,
                                                   u16* __restrict__ O) {
    __shared__ __align__(16) u16 Ks[2][64][72];     // [buf][key][d]
    __shared__ __align__(16) u16 Vs[2][64][72];     // [buf][d][key]
    __shared__ __align__(16) u16 Pt[8][16][72];     // [wave][q][key]
    const int t = threadIdx.x, w = t >> 6;
    const int m16 = t & 15, q4 = (t & 63) >> 4;
    const int bid = blockIdx.x;
    const int bx = (bid >> 3) & 7;                  // supertile-pair index
    const int bh = (bid & 7) + ((bid >> 6) << 3);   // head-batch; bh%8 == bid%8 == XCD
    const size_t base = (size_t)bh * 2048 * 64;
    const int b = bh >> 4, h = bh & 15;
    const int skey = t >> 3, sc = (t & 7) * 8;      // 16B staging per thread

#pragma unroll 1
    for (int ph = 0; ph < 2; ph++) {
        const int st = ph ? (15 - bx) : bx;
        const int qrow = st * 128 + w * 16 + m16;
        const u16* Qg = Q + base + (size_t)qrow * 64;
        bf16x8 qf0 = *(const bf16x8*)(Qg + q4 * 8);
        bf16x8 qf1 = *(const bf16x8*)(Qg + 32 + q4 * 8);

        f32x4 occ[4];
#pragma unroll
        for (int dc = 0; dc < 4; dc++) occ[dc] = zero4();
        float li = 0.f;

        const int jtmax = 2 * st + 1;
        const int jd = 2 * st + (w >> 2);   // this wave's diagonal tile

        const u16* Kb0 = Kg_ + base + skey * 64 + sc;            // + jt*4096
        const u16* Vt0 = Vtg_ + base + (size_t)skey * 2048 + sc; // + jt*64
        uint4 ka = *(const uint4*)(Kb0);
        uint4 va = *(const uint4*)(Vt0);

#pragma unroll 1
        for (int jt = 0; jt <= jtmax; jt++) {
            const int bi = jt & 1;
            *(uint4*)&Ks[bi][skey][sc] = ka;
            *(uint4*)&Vs[bi][skey][sc] = va;
            if (jt < jtmax) {
                ka = *(const uint4*)(Kb0 + (size_t)(jt + 1) * 4096);
                va = *(const uint4*)(Vt0 + (size_t)(jt + 1) * 64);
            }
            __syncthreads();   // single barrier per tile

            if (jt <= jd) {    // wave-uniform activity
                // S^T = K @ Q^T : col(m16)=q, key = c*16 + q4*4 + rr (log2 domain)
                f32x4 stv[4];
#pragma unroll
                for (int c = 0; c < 4; c++) stv[c] = zero4();
#pragma unroll
                for (int c = 0; c < 4; c++) {
                    bf16x8 kf0 = *(const bf16x8*)&Ks[bi][c * 16 + m16][q4 * 8];
                    bf16x8 kf1 = *(const bf16x8*)&Ks[bi][c * 16 + m16][32 + q4 * 8];
                    stv[c] = __builtin_amdgcn_mfma_f32_16x16x32_bf16(kf0, qf0, stv[c], 0, 0, 0);
                    stv[c] = __builtin_amdgcn_mfma_f32_16x16x32_bf16(kf1, qf1, stv[c], 0, 0, 0);
                }

                float pv[4][4];
#pragma unroll
                for (int c = 0; c < 4; c++)
#pragma unroll
                    for (int rr = 0; rr < 4; rr++) pv[c][rr] = stv[c][rr];
                if (jt == jd) {   // diagonal: mask key > q (lane-local q)
                    const int ql = qrow - 64 * jt;
#pragma unroll
                    for (int c = 0; c < 4; c++)
#pragma unroll
                        for (int rr = 0; rr < 4; rr++)
                            if (c * 16 + q4 * 4 + rr > ql) pv[c][rr] = -1e30f;
                }

                // fixed-max softmax: p = 2^(s' - 24)
#pragma unroll
                for (int c = 0; c < 4; c++) {
                    float p0 = ex2(pv[c][0] - 24.f);
                    float p1 = ex2(pv[c][1] - 24.f);
                    float p2 = ex2(pv[c][2] - 24.f);
                    float p3 = ex2(pv[c][3] - 24.f);
                    li += (p0 + p1) + (p2 + p3);
                    *(uint2*)&Pt[w][m16][c * 16 + q4 * 4] = make_uint2(pk2(p0, p1), pk2(p2, p3));
                }

                // O^T += V^T @ P^T
#pragma unroll
                for (int ks = 0; ks < 2; ks++) {
                    bf16x8 pf = *(const bf16x8*)&Pt[w][m16][ks * 32 + q4 * 8];
#pragma unroll
                    for (int dc = 0; dc < 4; dc++) {
                        bf16x8 vf = *(const bf16x8*)&Vs[bi][dc * 16 + m16][ks * 32 + q4 * 8];
                        occ[dc] = __builtin_amdgcn_mfma_f32_16x16x32_bf16(vf, pf, occ[dc], 0, 0, 0);
                    }
                }
            }
        }

        // epilogue: lane owns q-row qrow; d = dc*16 + q4*4 + rr
        li += __shfl_xor(li, 16);
        li += __shfl_xor(li, 32);
        float rli = 1.0f / li;
        u16* Op = O + ((size_t)(b * 2048 + qrow)) * 1024 + h * 64 + q4 * 4;
#pragma unroll
        for (int dc = 0; dc < 4; dc++) {
            ushort4 o;
            o.x = f2bf(occ[dc][0] * rli);
            o.y = f2bf(occ[dc][1] * rli);
            o.z = f2bf(occ[dc][2] * rli);
            o.w = f2bf(occ[dc][3] * rli);
            *(ushort4*)(Op + dc * 16) = o;
        }
        __syncthreads();  // protect LDS buffers across the phase boundary
    }
}

extern "C" void kernel_launch(void* const* d_in, const int* in_sizes, int n_in,
                              void* d_out, int out_size, void* d_ws, size_t ws_size,
                              hipStream_t stream) {
    const float* hs   = (const float*)d_in[0];
    const float* Wqkv = (const float*)d_in[2];
    const float* Wo   = (const float*)d_in[3];
    float* out = (float*)d_out;

    const int BS = 4096;
    const int H = 1024, N3 = 3072;
    const int SH = 32 * 2048 * 64;

    u16* Xb    = (u16*)d_ws;                 // [4096,1024]
    u16* Wqkvt = Xb + (size_t)BS * H;        // [3072,1024] (N-permuted, see prep)
    u16* Wot   = Wqkvt + (size_t)N3 * H;     // [1024,1024]
    u16* Qb    = Wot + (size_t)H * H;        // [bh][s][d]
    u16* Kb    = Qb + SH;
    u16* Vtb   = Kb + SH;                    // [bh][d][s] (written transposed)
    u16* AOb   = Vtb + SH;                   // [4096,1024] bf16
    float* cosT = (float*)(AOb + (size_t)BS * H);   // [2048][32]
    float* sinT = cosT + 2048 * 32;

    prep<<<8448, 256, 0, stream>>>(hs, Xb, Wqkv, Wqkvt, Wo, Wot, cosT, sinT);

    gemm_qkv<<<192, 512, 0, stream>>>(Xb, Wqkvt, cosT, sinT, Qb, Kb, Vtb);

    attn_kernel<<<256, 512, 0, stream>>>(Qb, Kb, Vtb, AOb);

    gemm_out<<<256, 256, 0, stream>>>(AOb, Wot, out);
}

// Round 10
// 186.167 us; speedup vs baseline: 1.1324x; 1.0138x over previous
//
#include <hip/hip_runtime.h>
#include <hip/hip_bf16.h>

typedef __bf16 bf16x8 __attribute__((ext_vector_type(8)));
typedef float f32x4 __attribute__((ext_vector_type(4)));
typedef unsigned short u16;

__device__ __forceinline__ u16 f2bf(float f) {
    union { float f; unsigned u; } x{f};
    unsigned r = x.u + 0x7fffu + ((x.u >> 16) & 1u);
    return (u16)(r >> 16);
}
// fast round-half-up pack of two fp32 -> packed bf16x2 (P >= 0, never NaN/Inf)
__device__ __forceinline__ unsigned pk2(float a, float b) {
    union { float f; unsigned u; } x{a}, y{b};
    return ((x.u + 0x8000u) >> 16) | ((y.u + 0x8000u) & 0xffff0000u);
}
// hardware exp2 (v_exp_f32); avoids glibc __exp2f macro collision
__device__ __forceinline__ float ex2(float x) { return __builtin_amdgcn_exp2f(x); }
__device__ __forceinline__ f32x4 zero4() { f32x4 z = {0.f, 0.f, 0.f, 0.f}; return z; }

// async global->LDS, 16B per lane; HW writes lane i at ldsbase + i*16
typedef const __attribute__((address_space(1))) unsigned int* gp1_t;
typedef __attribute__((address_space(3))) unsigned int* lp3_t;
__device__ __forceinline__ void async16(const u16* g, u16* l) {
    __builtin_amdgcn_global_load_lds((gp1_t)g, (lp3_t)l, 16, 0, 0);
}

// ======== prep: fused cast(hs->bf16) + W transposes + rope cos/sin tables ========
// blocks [0,4096): cast; [4096,7168): Wqkv^T (N-permuted for 8-phase gemm_qkv);
// [7168,8192): Wo^T; [8192,8448): tables
// Wqkvt perm (within each 256-col tile): orig (head hh, 16-frag f) -> position
// (f>>1)*8 + hh*2 + (f&1). Makes each gemm wave own one head with frag order
// f0,f1,f2,f3 at j=0..3 -> rope pairs (d, d+32) stay wave-local.
__global__ void __launch_bounds__(256) prep(const float* __restrict__ hs,
                                            u16* __restrict__ Xb,
                                            const float* __restrict__ Wqkv,
                                            u16* __restrict__ Wqkvt,
                                            const float* __restrict__ Wo,
                                            u16* __restrict__ Wot,
                                            float* __restrict__ cosT,
                                            float* __restrict__ sinT) {
    __shared__ float tile[32][33];
    const int blk = blockIdx.x, t = threadIdx.x;
    if (blk < 4096) {                       // cast 4096*1024 fp32 -> bf16
        int i = (blk * 256 + t) * 4;
        float4 v = *(const float4*)(hs + i);
        ushort4 o;
        o.x = f2bf(v.x); o.y = f2bf(v.y); o.z = f2bf(v.z); o.w = f2bf(v.w);
        *(ushort4*)(Xb + i) = o;
    } else if (blk < 8192) {                // transpose+cast W[K][N] -> Wt[N][K]
        const float* W; u16* Wt; int N, bx, by;
        bool qkv = (blk < 7168);
        if (qkv) { int bid = blk - 4096; W = Wqkv; Wt = Wqkvt; N = 3072; bx = bid % 96; by = bid / 96; }
        else     { int bid = blk - 7168; W = Wo;   Wt = Wot;   N = 1024; bx = bid % 32; by = bid / 32; }
        const int K = 1024;
        int tx = t & 31, ty = t >> 5;
        int n0 = bx * 32, k0 = by * 32;
#pragma unroll
        for (int i = 0; i < 32; i += 8)
            tile[ty + i][tx] = W[(size_t)(k0 + ty + i) * N + n0 + tx];
        __syncthreads();
#pragma unroll
        for (int i = 0; i < 32; i += 8) {
            int n = n0 + ty + i;
            int np = n;
            if (qkv) {
                int hh = (n >> 6) & 3, f = (n >> 4) & 3;
                np = (n & ~255) | (((f >> 1) * 8 + hh * 2 + (f & 1)) << 4) | (n & 15);
            }
            Wt[(size_t)np * K + k0 + tx] = f2bf(tile[tx][ty + i]);
        }
    } else {                                // rope tables: [2048][32] fp32
        int idx = (blk - 8192) * 256 + t;   // 65536
        int d = idx & 31, s = idx >> 5;
        float inv = expf(-(float)d * 0.374466538f);   // ln(160000)/32
        float th = (float)s * inv;
        cosT[idx] = cosf(th);
        sinT[idx] = sinf(th);
    }
}

// ======== 4-wave 128x128 GEMM K-loop (kept for gemm_out) ========
struct GemmCtx {
    f32x4 acc[4][4];
    int m16, q4, wm, wn;
};
template <int KDIM>
__device__ __forceinline__ void gemm_loop(const u16* __restrict__ A,
                                          const u16* __restrict__ Bt,
                                          int bm, int bn, GemmCtx& cx,
                                          u16* As, u16* Bs) {   // each [3][128*32]
    const int t = threadIdx.x;
    const int lane = t & 63, w = t >> 6;
    cx.wm = w >> 1; cx.wn = w & 1;
    cx.m16 = lane & 15; cx.q4 = lane >> 4;

    const int lrow = lane >> 2;
    const int kchunk = (lane & 3) ^ ((lane >> 3) & 3);   // swizzled global gather
    const u16* Ag = A + (size_t)(bm * 128 + w * 32 + lrow) * KDIM + kchunk * 8;
    const u16* Bg = Bt + (size_t)(bn * 128 + w * 32 + lrow) * KDIM + kchunk * 8;
    const int l0 = (w * 32) * 32;
    const int l1 = (w * 32 + 16) * 32;
    const int kswz = (cx.q4 ^ ((cx.m16 >> 1) & 3)) * 8;

#pragma unroll
    for (int i = 0; i < 4; i++)
#pragma unroll
        for (int j = 0; j < 4; j++) cx.acc[i][j] = zero4();

    constexpr int NT = KDIM / 32;
    // prologue: stage tiles 0,1 into buffers 0,1
    async16(Ag, As + l0);
    async16(Ag + 16 * KDIM, As + l1);
    async16(Bg, Bs + l0);
    async16(Bg + 16 * KDIM, Bs + l1);
    async16(Ag + 32, As + 4096 + l0);
    async16(Ag + 16 * KDIM + 32, As + 4096 + l1);
    async16(Bg + 32, Bs + 4096 + l0);
    async16(Bg + 16 * KDIM + 32, Bs + 4096 + l1);

    int co = 0, po = 2 * 4096;               // current / prefetch-dest buffer offsets
#pragma unroll 1
    for (int tt = 0; tt < NT; ++tt) {
        if (tt + 1 < NT) {
            asm volatile("s_waitcnt vmcnt(4)" ::: "memory");  // tile t landed
        } else {
            asm volatile("s_waitcnt vmcnt(0)" ::: "memory");
        }
        __builtin_amdgcn_s_barrier();
        __builtin_amdgcn_sched_barrier(0);
        if (tt + 2 < NT) {
            const int k0 = (tt + 2) * 32;
            async16(Ag + k0, As + po + l0);
            async16(Ag + 16 * KDIM + k0, As + po + l1);
            async16(Bg + k0, Bs + po + l0);
            async16(Bg + 16 * KDIM + k0, Bs + po + l1);
        }
        __builtin_amdgcn_sched_barrier(0);

        bf16x8 af[4], bf[4];
#pragma unroll
        for (int i = 0; i < 4; i++)
            af[i] = *(const bf16x8*)&As[co + (cx.wm * 64 + i * 16 + cx.m16) * 32 + kswz];
#pragma unroll
        for (int j = 0; j < 4; j++)
            bf[j] = *(const bf16x8*)&Bs[co + (cx.wn * 64 + j * 16 + cx.m16) * 32 + kswz];
#pragma unroll
        for (int i = 0; i < 4; i++)
#pragma unroll
            for (int j = 0; j < 4; j++)
                cx.acc[i][j] = __builtin_amdgcn_mfma_f32_16x16x32_bf16(af[i], bf[j], cx.acc[i][j], 0, 0, 0);

        asm volatile("" ::: "memory");
        __builtin_amdgcn_sched_barrier(0);
        co += 4096; if (co == 12288) co = 0;
        po += 4096; if (po == 12288) po = 0;
    }
}

// ======== gemm_qkv: 256^2, BK=64, 8 waves, 8-PHASE fine interleave (T2+T3+T4+T5) ====
// Each K-tile = 4 sub-phases {ds_read subtile || stage 1 half-tile -> barrier ->
// 16 MFMA (setprio) -> barrier}. A-frags live 2 phases, B-frags live whole tile ->
// LDS reads stay at 24/wave/tile. Stage schedule (into buf[T&1] / other buf):
// q0: A-high(T+1), q1: B-high(T+1), q2: A-low(T+2), q3: B-low(T+2) + vmcnt(4).
// Swizzle: LDS slot s of row r holds global k-chunk s ^ (r&7) (lane-local gather
// pre-swizzle); read slot = (ks*4+q4) ^ (m16&7) -> conflict-free (R4: conflicts=0).
__global__ void __launch_bounds__(512, 2) gemm_qkv(const u16* __restrict__ A,
                                                   const u16* __restrict__ Bt,
                                                   const float* __restrict__ cosT,
                                                   const float* __restrict__ sinT,
                                                   u16* __restrict__ Q,
                                                   u16* __restrict__ Kd,
                                                   u16* __restrict__ Vt) {
    __shared__ __align__(16) u16 As[2 * 256 * 64];
    __shared__ __align__(16) u16 Bs[2 * 256 * 64];
    constexpr int HB = 256 * 64;
    const int t = threadIdx.x, lane = t & 63, w = t >> 6;
    const int wm = w >> 2, wn = w & 3;
    const int m16 = lane & 15, q4 = lane >> 4, m7 = m16 & 7;
    const int hw = blockIdx.x;
    const int orig = (hw & 7) * 24 + (hw >> 3);   // bijective XCD swizzle: 192 = 8*24
    const int bm = orig / 12, bn = orig % 12;

    const int srow = lane >> 3;
    const int schunk = (lane & 7) ^ srow;
    const u16* Ag = A + (size_t)(bm * 256 + w * 8 + srow) * 1024 + schunk * 8;
    const u16* Bg = Bt + (size_t)(bn * 256 + w * 8 + srow) * 1024 + schunk * 8;
    u16* AsW = As + w * 512;     // wave's 8-row stage slab base
    u16* BsW = Bs + w * 512;

    f32x4 acc[8][4];
#pragma unroll
    for (int i = 0; i < 8; i++)
#pragma unroll
        for (int j = 0; j < 4; j++) acc[i][j] = zero4();

    const int slt0 = (q4 ^ m7) * 8;          // ks=0 read slot (u16 units)
    const int slt1 = ((4 + q4) ^ m7) * 8;    // ks=1

// stage one half-tile (2 async16/thread): half H of K-tile S, operand A/B
#define STGA(S, H) do { const u16* g_ = Ag + (size_t)(H) * 131072 + (S) * 64; \
    u16* l_ = AsW + ((S) & 1) * HB + (H) * 8192; \
    async16(g_, l_); async16(g_ + 65536, l_ + 4096); } while (0)
#define STGB(S, H) do { const u16* g_ = Bg + (size_t)(H) * 131072 + (S) * 64; \
    u16* l_ = BsW + ((S) & 1) * HB + (H) * 8192; \
    async16(g_, l_); async16(g_ + 65536, l_ + 4096); } while (0)

    // prologue: tile0 all 4 halves + tile1 A-low, B-low (12 loads/thread)
    STGA(0, 0); STGB(0, 0); STGA(0, 1); STGB(0, 1); STGA(1, 0); STGB(1, 0);
    asm volatile("s_waitcnt vmcnt(4)" ::: "memory");   // tile 0 landed
    __builtin_amdgcn_sched_barrier(0);
    __builtin_amdgcn_s_barrier();

#define MFMA8(IB, B0, B1) do { \
    _Pragma("unroll") for (int i4 = 0; i4 < 4; i4++) \
    _Pragma("unroll") for (int j2 = 0; j2 < 2; j2++) \
        acc[(IB) + i4][(JB) + j2] = __builtin_amdgcn_mfma_f32_16x16x32_bf16(a0[i4], B0[j2], acc[(IB) + i4][(JB) + j2], 0, 0, 0); \
    _Pragma("unroll") for (int i4 = 0; i4 < 4; i4++) \
    _Pragma("unroll") for (int j2 = 0; j2 < 2; j2++) \
        acc[(IB) + i4][(JB) + j2] = __builtin_amdgcn_mfma_f32_16x16x32_bf16(a1[i4], B1[j2], acc[(IB) + i4][(JB) + j2], 0, 0, 0); \
} while (0)

#define BAR1() do { __builtin_amdgcn_sched_barrier(0); __builtin_amdgcn_s_barrier(); \
                    __builtin_amdgcn_s_setprio(1); } while (0)
#define BAR2() do { __builtin_amdgcn_s_setprio(0); asm volatile("" ::: "memory"); \
                    __builtin_amdgcn_sched_barrier(0); __builtin_amdgcn_s_barrier(); } while (0)

#pragma unroll 1
    for (int T = 0; T < 16; ++T) {
        const int co = (T & 1) * HB;
        const int aL = co + (wm * 64 + m16) * 64;
        const int aH = aL + 128 * 64;
        const int bL = co + (wn * 32 + m16) * 64;
        const int bH = bL + 128 * 64;
        bf16x8 a0[4], a1[4], pl0[2], pl1[2], ph0[2], ph1[2];

        // ---- q0: read A-low + B-low; stage A-high(T+1); MFMA quad (lowA, lowB) ----
#pragma unroll
        for (int i4 = 0; i4 < 4; i4++) {
            a0[i4] = *(const bf16x8*)&As[aL + i4 * 1024 + slt0];
            a1[i4] = *(const bf16x8*)&As[aL + i4 * 1024 + slt1];
        }
#pragma unroll
        for (int j2 = 0; j2 < 2; j2++) {
            pl0[j2] = *(const bf16x8*)&Bs[bL + j2 * 1024 + slt0];
            pl1[j2] = *(const bf16x8*)&Bs[bL + j2 * 1024 + slt1];
        }
        if (T < 15) STGA(T + 1, 1);
        BAR1();
        { constexpr int JB = 0; MFMA8(0, pl0, pl1); }
        BAR2();

        // ---- q1: read B-high; stage B-high(T+1); MFMA (lowA, highB) reusing a0/a1 ----
#pragma unroll
        for (int j2 = 0; j2 < 2; j2++) {
            ph0[j2] = *(const bf16x8*)&Bs[bH + j2 * 1024 + slt0];
            ph1[j2] = *(const bf16x8*)&Bs[bH + j2 * 1024 + slt1];
        }
        if (T < 15) STGB(T + 1, 1);
        BAR1();
        { constexpr int JB = 2; MFMA8(0, ph0, ph1); }
        BAR2();

        // ---- q2: reload A-high; stage A-low(T+2); MFMA (highA, lowB) reusing pl ----
#pragma unroll
        for (int i4 = 0; i4 < 4; i4++) {
            a0[i4] = *(const bf16x8*)&As[aH + i4 * 1024 + slt0];
            a1[i4] = *(const bf16x8*)&As[aH + i4 * 1024 + slt1];
        }
        if (T < 14) STGA(T + 2, 0);
        BAR1();
        { constexpr int JB = 0; MFMA8(4, pl0, pl1); }
        BAR2();

        // ---- q3: no reads; stage B-low(T+2) + vmcnt; MFMA (highA, highB) ----
        if (T < 14) {
            STGB(T + 2, 0);
            asm volatile("s_waitcnt vmcnt(4)" ::: "memory");  // tile T+1 landed
        } else {
            asm volatile("s_waitcnt vmcnt(0)" ::: "memory");
        }
        BAR1();
        { constexpr int JB = 2; MFMA8(4, ph0, ph1); }
        BAR2();
    }
#undef STGA
#undef STGB
#undef MFMA8
#undef BAR1
#undef BAR2

    // ==== epilogue: wave = one (type, head) via virtual colbase (perm baked in W) ====
    const int colbase = bn * 256 + wn * 64;
    const int type = colbase >> 10;            // 0=Q 1=K 2=V
    const int h = (colbase & 1023) >> 6;

    if (type == 2) {
        // V transposed: Vt[bh][d][s]; lane's rr=0..3 are 4 consecutive s -> 8B store
#pragma unroll
        for (int i = 0; i < 8; i++) {
            int sr = bm * 256 + (i >> 2) * 128 + wm * 64 + (i & 3) * 16 + q4 * 4;
            int b = sr >> 11, sl = sr & 2047;
            size_t ob = (size_t)(b * 16 + h) * 64 * 2048;
#pragma unroll
            for (int j = 0; j < 4; j++) {
                int d = j * 16 + m16;
                ushort4 o;
                o.x = f2bf(acc[i][j][0]);
                o.y = f2bf(acc[i][j][1]);
                o.z = f2bf(acc[i][j][2]);
                o.w = f2bf(acc[i][j][3]);
                *(ushort4*)&Vt[ob + (size_t)d * 2048 + sl] = o;
            }
        }
    } else {
        u16* dst = (type == 0) ? Q : Kd;
        const float qs = (type == 0) ? 0.1803368801f /*0.125*log2(e)*/ : 1.0f;
#pragma unroll
        for (int i = 0; i < 8; i++)
#pragma unroll
            for (int rr = 0; rr < 4; rr++) {
                int r = bm * 256 + (i >> 2) * 128 + wm * 64 + (i & 3) * 16 + q4 * 4 + rr;
                int b = r >> 11, s = r & 2047;
                size_t ob = ((size_t)((b * 16 + h) * 2048 + s)) * 64;
#pragma unroll
                for (int j2 = 0; j2 < 2; j2++) {
                    int d = j2 * 16 + m16;                 // d in [0,32)
                    float cs = cosT[s * 32 + d];
                    float sn = sinT[s * 32 + d];
                    float x1 = acc[i][j2][rr];
                    float x2 = acc[i][j2 + 2][rr];
                    dst[ob + d]      = f2bf((x1 * cs - x2 * sn) * qs);
                    dst[ob + d + 32] = f2bf((x2 * cs + x1 * sn) * qs);
                }
            }
    }
}

// ---------------- out-proj GEMM: C[M,N] fp32 = A[M,K] @ Bt[N,K]^T ----------------
// 1D grid 256, chunked XCD swizzle (256 = 8*32): each XCD gets 4 bm-panels (1MB)
// + full Bt (2MB) -> 3MB L2-resident, Bt/A fetched once per XCD.
__global__ void __launch_bounds__(256) gemm_out(const u16* __restrict__ A,
                                                const u16* __restrict__ Bt,
                                                float* __restrict__ C) {
    __shared__ __align__(16) u16 As[3 * 128 * 32];
    __shared__ __align__(16) u16 Bs[3 * 128 * 32];
    GemmCtx cx;
    const int hw = blockIdx.x;
    const int orig = (hw & 7) * 32 + (hw >> 3);   // bijective: 256 % 8 == 0
    const int bm = orig >> 3, bn = orig & 7;
    gemm_loop<1024>(A, Bt, bm, bn, cx, As, Bs);
    const int N = 1024;
#pragma unroll
    for (int i = 0; i < 4; i++)
#pragma unroll
        for (int j = 0; j < 4; j++)
#pragma unroll
            for (int rr = 0; rr < 4; rr++) {
                int row = bm * 128 + cx.wm * 64 + i * 16 + cx.q4 * 4 + rr;
                int col = bn * 128 + cx.wn * 64 + j * 16 + cx.m16;
                C[(size_t)row * N + col] = cx.acc[i][j][rr];
            }
}

// ---------------- causal flash attention: 512 blocks, ONE supertile per block ----------------
// 1D grid 512, 2 blocks/CU (16 waves/CU — double R9's occupancy; LDS 55KB*2 fits).
// bid<256: st = 15-(bid>>5) (heavy supertiles launch first), bh = bid&31;
// bid>=256: st = (bid-256)>>5 (light), bh = (bid-256)&31.
// Round-robin dispatch co-locates bid c and c+256 on one CU: st pair sums to 15 ->
// exactly 34 tiles per CU (preserves the pair scheme's perfect balance), same bh ->
// K/V shared in that XCD's L2 (keeps R9's FETCH win: 12MB).
// Each wave owns one 16-q-row group; per-thread staging 16B K + 16B V per tile.
// Waves whose diagonal tile jd = 2*st + (w>=4) has passed skip compute but keep
// barriers. S^T = mfma(K_frag, Q_frag); fixed exponent offset M=24; 1 barrier/tile.
__global__ void __launch_bounds__(512) attn_kernel(const u16* __restrict__ Q,
                                                   const u16* __restrict__ Kg_,
                                                   const u16* __restrict__ Vtg_,
                                                   u16* __restrict__ O) {
    __shared__ __align__(16) u16 Ks[2][64][72];     // [buf][key][d]
    __shared__ __align__(16) u16 Vs[2][64][72];     // [buf][d][key]
    __shared__ __align__(16) u16 Pt[8][16][72];     // [wave][q][key]
    const int t = threadIdx.x, w = t >> 6;
    const int m16 = t & 15, q4 = (t & 63) >> 4;
    const int bid = blockIdx.x;
    const int c = bid & 255;
    const int st = (bid < 256) ? (15 - (c >> 5)) : (c >> 5);
    const int bh = c & 31;
    const size_t base = (size_t)bh * 2048 * 64;
    const int b = bh >> 4, h = bh & 15;
    const int skey = t >> 3, sc = (t & 7) * 8;      // 16B staging per thread

    const int qrow = st * 128 + w * 16 + m16;
    const u16* Qg = Q + base + (size_t)qrow * 64;
    bf16x8 qf0 = *(const bf16x8*)(Qg + q4 * 8);
    bf16x8 qf1 = *(const bf16x8*)(Qg + 32 + q4 * 8);

    f32x4 occ[4];
#pragma unroll
    for (int dc = 0; dc < 4; dc++) occ[dc] = zero4();
    float li = 0.f;

    const int jtmax = 2 * st + 1;
    const int jd = 2 * st + (w >> 2);   // this wave's diagonal tile

    const u16* Kb0 = Kg_ + base + skey * 64 + sc;            // + jt*4096
    const u16* Vt0 = Vtg_ + base + (size_t)skey * 2048 + sc; // + jt*64
    uint4 ka = *(const uint4*)(Kb0);
    uint4 va = *(const uint4*)(Vt0);

#pragma unroll 1
    for (int jt = 0; jt <= jtmax; jt++) {
        const int bi = jt & 1;
        *(uint4*)&Ks[bi][skey][sc] = ka;
        *(uint4*)&Vs[bi][skey][sc] = va;
        if (jt < jtmax) {
            ka = *(const uint4*)(Kb0 + (size_t)(jt + 1) * 4096);
            va = *(const uint4*)(Vt0 + (size_t)(jt + 1) * 64);
        }
        __syncthreads();   // single barrier per tile

        if (jt <= jd) {    // wave-uniform activity
            // S^T = K @ Q^T : col(m16)=q, key = c*16 + q4*4 + rr (log2 domain)
            f32x4 stv[4];
#pragma unroll
            for (int cc = 0; cc < 4; cc++) stv[cc] = zero4();
#pragma unroll
            for (int cc = 0; cc < 4; cc++) {
                bf16x8 kf0 = *(const bf16x8*)&Ks[bi][cc * 16 + m16][q4 * 8];
                bf16x8 kf1 = *(const bf16x8*)&Ks[bi][cc * 16 + m16][32 + q4 * 8];
                stv[cc] = __builtin_amdgcn_mfma_f32_16x16x32_bf16(kf0, qf0, stv[cc], 0, 0, 0);
                stv[cc] = __builtin_amdgcn_mfma_f32_16x16x32_bf16(kf1, qf1, stv[cc], 0, 0, 0);
            }

            float pv[4][4];
#pragma unroll
            for (int cc = 0; cc < 4; cc++)
#pragma unroll
                for (int rr = 0; rr < 4; rr++) pv[cc][rr] = stv[cc][rr];
            if (jt == jd) {   // diagonal: mask key > q (lane-local q)
                const int ql = qrow - 64 * jt;
#pragma unroll
                for (int cc = 0; cc < 4; cc++)
#pragma unroll
                    for (int rr = 0; rr < 4; rr++)
                        if (cc * 16 + q4 * 4 + rr > ql) pv[cc][rr] = -1e30f;
            }

            // fixed-max softmax: p = 2^(s' - 24)
#pragma unroll
            for (int cc = 0; cc < 4; cc++) {
                float p0 = ex2(pv[cc][0] - 24.f);
                float p1 = ex2(pv[cc][1] - 24.f);
                float p2 = ex2(pv[cc][2] - 24.f);
                float p3 = ex2(pv[cc][3] - 24.f);
                li += (p0 + p1) + (p2 + p3);
                *(uint2*)&Pt[w][m16][cc * 16 + q4 * 4] = make_uint2(pk2(p0, p1), pk2(p2, p3));
            }

            // O^T += V^T @ P^T
#pragma unroll
            for (int ks = 0; ks < 2; ks++) {
                bf16x8 pf = *(const bf16x8*)&Pt[w][m16][ks * 32 + q4 * 8];
#pragma unroll
                for (int dc = 0; dc < 4; dc++) {
                    bf16x8 vf = *(const bf16x8*)&Vs[bi][dc * 16 + m16][ks * 32 + q4 * 8];
                    occ[dc] = __builtin_amdgcn_mfma_f32_16x16x32_bf16(vf, pf, occ[dc], 0, 0, 0);
                }
            }
        }
    }

    // epilogue: lane owns q-row qrow; d = dc*16 + q4*4 + rr
    li += __shfl_xor(li, 16);
    li += __shfl_xor(li, 32);
    float rli = 1.0f / li;
    u16* Op = O + ((size_t)(b * 2048 + qrow)) * 1024 + h * 64 + q4 * 4;
#pragma unroll
    for (int dc = 0; dc < 4; dc++) {
        ushort4 o;
        o.x = f2bf(occ[dc][0] * rli);
        o.y = f2bf(occ[dc][1] * rli);
        o.z = f2bf(occ[dc][2] * rli);
        o.w = f2bf(occ[dc][3] * rli);
        *(ushort4*)(Op + dc * 16) = o;
    }
}

extern "C" void kernel_launch(void* const* d_in, const int* in_sizes, int n_in,
                              void* d_out, int out_size, void* d_ws, size_t ws_size,
                              hipStream_t stream) {
    const float* hs   = (const float*)d_in[0];
    const float* Wqkv = (const float*)d_in[2];
    const float* Wo   = (const float*)d_in[3];
    float* out = (float*)d_out;

    const int BS = 4096;
    const int H = 1024, N3 = 3072;
    const int SH = 32 * 2048 * 64;

    u16* Xb    = (u16*)d_ws;                 // [4096,1024]
    u16* Wqkvt = Xb + (size_t)BS * H;        // [3072,1024] (N-permuted, see prep)
    u16* Wot   = Wqkvt + (size_t)N3 * H;     // [1024,1024]
    u16* Qb    = Wot + (size_t)H * H;        // [bh][s][d]
    u16* Kb    = Qb + SH;
    u16* Vtb   = Kb + SH;                    // [bh][d][s] (written transposed)
    u16* AOb   = Vtb + SH;                   // [4096,1024] bf16
    float* cosT = (float*)(AOb + (size_t)BS * H);   // [2048][32]
    float* sinT = cosT + 2048 * 32;

    prep<<<8448, 256, 0, stream>>>(hs, Xb, Wqkv, Wqkvt, Wo, Wot, cosT, sinT);

    gemm_qkv<<<192, 512, 0, stream>>>(Xb, Wqkvt, cosT, sinT, Qb, Kb, Vtb);

    attn_kernel<<<512, 512, 0, stream>>>(Qb, Kb, Vtb, AOb);

    gemm_out<<<256, 256, 0, stream>>>(AOb, Wot, out);
}

// Round 11
// 182.140 us; speedup vs baseline: 1.1574x; 1.0221x over previous
//
#include <hip/hip_runtime.h>
#include <hip/hip_bf16.h>

typedef __bf16 bf16x8 __attribute__((ext_vector_type(8)));
typedef float f32x4 __attribute__((ext_vector_type(4)));
typedef unsigned short u16;

__device__ __forceinline__ u16 f2bf(float f) {
    union { float f; unsigned u; } x{f};
    unsigned r = x.u + 0x7fffu + ((x.u >> 16) & 1u);
    return (u16)(r >> 16);
}
// fast round-half-up pack of two fp32 -> packed bf16x2 (P >= 0, never NaN/Inf)
__device__ __forceinline__ unsigned pk2(float a, float b) {
    union { float f; unsigned u; } x{a}, y{b};
    return ((x.u + 0x8000u) >> 16) | ((y.u + 0x8000u) & 0xffff0000u);
}
// hardware exp2 (v_exp_f32); avoids glibc __exp2f macro collision
__device__ __forceinline__ float ex2(float x) { return __builtin_amdgcn_exp2f(x); }
__device__ __forceinline__ f32x4 zero4() { f32x4 z = {0.f, 0.f, 0.f, 0.f}; return z; }

// async global->LDS, 16B per lane; HW writes lane i at ldsbase + i*16
typedef const __attribute__((address_space(1))) unsigned int* gp1_t;
typedef __attribute__((address_space(3))) unsigned int* lp3_t;
__device__ __forceinline__ void async16(const u16* g, u16* l) {
    __builtin_amdgcn_global_load_lds((gp1_t)g, (lp3_t)l, 16, 0, 0);
}

// ======== prep: fused cast(hs->bf16) + W transposes + rope cos/sin tables ========
// blocks [0,4096): cast; [4096,7168): Wqkv^T; [7168,8192): Wo^T; [8192,8448): tables
// (natural N order — the 6-wave gemm_qkv reads B-frags contiguously, no perm needed)
__global__ void __launch_bounds__(256) prep(const float* __restrict__ hs,
                                            u16* __restrict__ Xb,
                                            const float* __restrict__ Wqkv,
                                            u16* __restrict__ Wqkvt,
                                            const float* __restrict__ Wo,
                                            u16* __restrict__ Wot,
                                            float* __restrict__ cosT,
                                            float* __restrict__ sinT) {
    __shared__ float tile[32][33];
    const int blk = blockIdx.x, t = threadIdx.x;
    if (blk < 4096) {                       // cast 4096*1024 fp32 -> bf16
        int i = (blk * 256 + t) * 4;
        float4 v = *(const float4*)(hs + i);
        ushort4 o;
        o.x = f2bf(v.x); o.y = f2bf(v.y); o.z = f2bf(v.z); o.w = f2bf(v.w);
        *(ushort4*)(Xb + i) = o;
    } else if (blk < 8192) {                // transpose+cast W[K][N] -> Wt[N][K]
        const float* W; u16* Wt; int N, bx, by;
        if (blk < 7168) { int bid = blk - 4096; W = Wqkv; Wt = Wqkvt; N = 3072; bx = bid % 96; by = bid / 96; }
        else            { int bid = blk - 7168; W = Wo;   Wt = Wot;   N = 1024; bx = bid % 32; by = bid / 32; }
        const int K = 1024;
        int tx = t & 31, ty = t >> 5;
        int n0 = bx * 32, k0 = by * 32;
#pragma unroll
        for (int i = 0; i < 32; i += 8)
            tile[ty + i][tx] = W[(size_t)(k0 + ty + i) * N + n0 + tx];
        __syncthreads();
#pragma unroll
        for (int i = 0; i < 32; i += 8)
            Wt[(size_t)(n0 + ty + i) * K + k0 + tx] = f2bf(tile[tx][ty + i]);
    } else {                                // rope tables: [2048][32] fp32
        int idx = (blk - 8192) * 256 + t;   // 65536
        int d = idx & 31, s = idx >> 5;
        float inv = expf(-(float)d * 0.374466538f);   // ln(160000)/32
        float th = (float)s * inv;
        cosT[idx] = cosf(th);
        sinT[idx] = sinf(th);
    }
}

// ======== 4-wave 128x128 GEMM K-loop (kept for gemm_out) ========
struct GemmCtx {
    f32x4 acc[4][4];
    int m16, q4, wm, wn;
};
template <int KDIM>
__device__ __forceinline__ void gemm_loop(const u16* __restrict__ A,
                                          const u16* __restrict__ Bt,
                                          int bm, int bn, GemmCtx& cx,
                                          u16* As, u16* Bs) {   // each [3][128*32]
    const int t = threadIdx.x;
    const int lane = t & 63, w = t >> 6;
    cx.wm = w >> 1; cx.wn = w & 1;
    cx.m16 = lane & 15; cx.q4 = lane >> 4;

    const int lrow = lane >> 2;
    const int kchunk = (lane & 3) ^ ((lane >> 3) & 3);   // swizzled global gather
    const u16* Ag = A + (size_t)(bm * 128 + w * 32 + lrow) * KDIM + kchunk * 8;
    const u16* Bg = Bt + (size_t)(bn * 128 + w * 32 + lrow) * KDIM + kchunk * 8;
    const int l0 = (w * 32) * 32;
    const int l1 = (w * 32 + 16) * 32;
    const int kswz = (cx.q4 ^ ((cx.m16 >> 1) & 3)) * 8;

#pragma unroll
    for (int i = 0; i < 4; i++)
#pragma unroll
        for (int j = 0; j < 4; j++) cx.acc[i][j] = zero4();

    constexpr int NT = KDIM / 32;
    // prologue: stage tiles 0,1 into buffers 0,1
    async16(Ag, As + l0);
    async16(Ag + 16 * KDIM, As + l1);
    async16(Bg, Bs + l0);
    async16(Bg + 16 * KDIM, Bs + l1);
    async16(Ag + 32, As + 4096 + l0);
    async16(Ag + 16 * KDIM + 32, As + 4096 + l1);
    async16(Bg + 32, Bs + 4096 + l0);
    async16(Bg + 16 * KDIM + 32, Bs + 4096 + l1);

    int co = 0, po = 2 * 4096;               // current / prefetch-dest buffer offsets
#pragma unroll 1
    for (int tt = 0; tt < NT; ++tt) {
        if (tt + 1 < NT) {
            asm volatile("s_waitcnt vmcnt(4)" ::: "memory");  // tile t landed
        } else {
            asm volatile("s_waitcnt vmcnt(0)" ::: "memory");
        }
        __builtin_amdgcn_s_barrier();
        __builtin_amdgcn_sched_barrier(0);
        if (tt + 2 < NT) {
            const int k0 = (tt + 2) * 32;
            async16(Ag + k0, As + po + l0);
            async16(Ag + 16 * KDIM + k0, As + po + l1);
            async16(Bg + k0, Bs + po + l0);
            async16(Bg + 16 * KDIM + k0, Bs + po + l1);
        }
        __builtin_amdgcn_sched_barrier(0);

        bf16x8 af[4], bf[4];
#pragma unroll
        for (int i = 0; i < 4; i++)
            af[i] = *(const bf16x8*)&As[co + (cx.wm * 64 + i * 16 + cx.m16) * 32 + kswz];
#pragma unroll
        for (int j = 0; j < 4; j++)
            bf[j] = *(const bf16x8*)&Bs[co + (cx.wn * 64 + j * 16 + cx.m16) * 32 + kswz];
#pragma unroll
        for (int i = 0; i < 4; i++)
#pragma unroll
            for (int j = 0; j < 4; j++)
                cx.acc[i][j] = __builtin_amdgcn_mfma_f32_16x16x32_bf16(af[i], bf[j], cx.acc[i][j], 0, 0, 0);

        asm volatile("" ::: "memory");
        __builtin_amdgcn_sched_barrier(0);
        co += 4096; if (co == 12288) co = 0;
        po += 4096; if (po == 12288) po = 0;
    }
}

// ======== gemm_qkv: 256x192 tile, BK=64, 6 waves (2M x 3N), 8-phase interleave ====
// Grid 16x16 = 256 blocks = EXACTLY 1/CU (R10 had 192/256 = 75% coverage; full
// coverage at per-CU work 100.7 MF with AI 109.7 B/FLOP). Wave = 128x64, acc[8][4],
// sub-phase schedule/reads/swizzle identical to the verified 256^2 8-phase kernel.
// Staging in 64-chunk wave-groups g = w + 6k (8g==0 mod 8 keeps gather pre-swizzle
// gk = (l&7)^((l>>3)&7) row-invariant). A halves at q0/q2 (16 groups: waves 0-3 x3,
// 4-5 x2); B whole at q1 (24 groups: 4/wave). vmcnt(2) conservative for both classes.
// LDS: A 2x32KB + B 2x24KB = 112KB -> 1 block/CU. Natural N order (no perm): wave wn
// owns cols [wn*64,wn*64+64) contiguously -> rope pairs (d,d+32) = acc[.][j2],[j2+2].
__global__ void __launch_bounds__(384) gemm_qkv(const u16* __restrict__ A,
                                                const u16* __restrict__ Bt,
                                                const float* __restrict__ cosT,
                                                const float* __restrict__ sinT,
                                                u16* __restrict__ Q,
                                                u16* __restrict__ Kd,
                                                u16* __restrict__ Vt) {
    __shared__ __align__(16) u16 As[2 * 256 * 64];   // 64 KB
    __shared__ __align__(16) u16 Bs[2 * 192 * 64];   // 48 KB
    const int t = threadIdx.x, lane = t & 63, w = t >> 6;   // 6 waves
    const int wm = (w >= 3) ? 1 : 0, wn = w - wm * 3;
    const int m16 = lane & 15, q4 = lane >> 4, m7 = m16 & 7;
    const int hw = blockIdx.x;
    const int orig = (hw & 7) * 32 + (hw >> 3);   // bijective XCD swizzle: 256 = 8*32
    const int bm = orig >> 4, bn = orig & 15;

    const int l8 = lane >> 3;
    const int gk = (lane & 7) ^ l8;               // pre-swizzled global k-chunk
    const u16* AgB = A + (size_t)(bm * 256 + 8 * w + l8) * 1024 + gk * 8;
    const u16* BgB = Bt + (size_t)(bn * 192 + 8 * w + l8) * 1024 + gk * 8;

    f32x4 acc[8][4];
#pragma unroll
    for (int i = 0; i < 8; i++)
#pragma unroll
        for (int j = 0; j < 4; j++) acc[i][j] = zero4();

    const int slt0 = (q4 ^ m7) * 8;          // ks=0 read slot (u16 units)
    const int slt1 = ((4 + q4) ^ m7) * 8;    // ks=1

// stage wave-group k of half H (A) / of whole tile (B) for K-tile S
#define STGA(S, H, K) async16(AgB + (size_t)((H) * 128 + 48 * (K)) * 1024 + (S) * 64, \
                              As + ((S) & 1) * 16384 + (H) * 8192 + w * 512 + (K) * 3072)
#define STGB(S, K)    async16(BgB + (size_t)(48 * (K)) * 1024 + (S) * 64, \
                              Bs + ((S) & 1) * 12288 + w * 512 + (K) * 3072)
#define STGAH(S, H) do { STGA(S, H, 0); STGA(S, H, 1); if (w < 4) STGA(S, H, 2); } while (0)
#define STGBF(S)    do { STGB(S, 0); STGB(S, 1); STGB(S, 2); STGB(S, 3); } while (0)

    // prologue: tile0 (A-low, A-high, B) + tile1 A-low
    STGAH(0, 0); STGAH(0, 1); STGBF(0); STGAH(1, 0);
    asm volatile("s_waitcnt vmcnt(2)" ::: "memory");   // tile 0 landed
    __builtin_amdgcn_sched_barrier(0);
    __builtin_amdgcn_s_barrier();

#define MFMA8(IB, B0, B1) do { \
    _Pragma("unroll") for (int i4 = 0; i4 < 4; i4++) \
    _Pragma("unroll") for (int j2 = 0; j2 < 2; j2++) \
        acc[(IB) + i4][(JB) + j2] = __builtin_amdgcn_mfma_f32_16x16x32_bf16(a0[i4], B0[j2], acc[(IB) + i4][(JB) + j2], 0, 0, 0); \
    _Pragma("unroll") for (int i4 = 0; i4 < 4; i4++) \
    _Pragma("unroll") for (int j2 = 0; j2 < 2; j2++) \
        acc[(IB) + i4][(JB) + j2] = __builtin_amdgcn_mfma_f32_16x16x32_bf16(a1[i4], B1[j2], acc[(IB) + i4][(JB) + j2], 0, 0, 0); \
} while (0)

#define BAR1() do { __builtin_amdgcn_sched_barrier(0); __builtin_amdgcn_s_barrier(); \
                    __builtin_amdgcn_s_setprio(1); } while (0)
#define BAR2() do { __builtin_amdgcn_s_setprio(0); asm volatile("" ::: "memory"); \
                    __builtin_amdgcn_sched_barrier(0); __builtin_amdgcn_s_barrier(); } while (0)

#pragma unroll 1
    for (int T = 0; T < 16; ++T) {
        const int aL = (T & 1) * 16384 + (wm * 64 + m16) * 64;
        const int aH = aL + 8192;
        const int bB = (T & 1) * 12288 + (wn * 64 + m16) * 64;
        bf16x8 a0[4], a1[4], pl0[2], pl1[2], ph0[2], ph1[2];

        // ---- q0: read A-low + B(j=0,1); stage A-high(T+1); MFMA (lowA, B01) ----
#pragma unroll
        for (int i4 = 0; i4 < 4; i4++) {
            a0[i4] = *(const bf16x8*)&As[aL + i4 * 1024 + slt0];
            a1[i4] = *(const bf16x8*)&As[aL + i4 * 1024 + slt1];
        }
#pragma unroll
        for (int j2 = 0; j2 < 2; j2++) {
            pl0[j2] = *(const bf16x8*)&Bs[bB + j2 * 1024 + slt0];
            pl1[j2] = *(const bf16x8*)&Bs[bB + j2 * 1024 + slt1];
        }
        if (T < 15) STGAH(T + 1, 1);
        BAR1();
        { constexpr int JB = 0; MFMA8(0, pl0, pl1); }
        BAR2();

        // ---- q1: read B(j=2,3); stage B(T+1); MFMA (lowA, B23) reusing a0/a1 ----
#pragma unroll
        for (int j2 = 0; j2 < 2; j2++) {
            ph0[j2] = *(const bf16x8*)&Bs[bB + (j2 + 2) * 1024 + slt0];
            ph1[j2] = *(const bf16x8*)&Bs[bB + (j2 + 2) * 1024 + slt1];
        }
        if (T < 15) STGBF(T + 1);
        BAR1();
        { constexpr int JB = 2; MFMA8(0, ph0, ph1); }
        BAR2();

        // ---- q2: read A-high; stage A-low(T+2); MFMA (highA, B01) reusing pl ----
#pragma unroll
        for (int i4 = 0; i4 < 4; i4++) {
            a0[i4] = *(const bf16x8*)&As[aH + i4 * 1024 + slt0];
            a1[i4] = *(const bf16x8*)&As[aH + i4 * 1024 + slt1];
        }
        if (T < 14) STGAH(T + 2, 0);
        BAR1();
        { constexpr int JB = 0; MFMA8(4, pl0, pl1); }
        BAR2();

        // ---- q3: vmcnt (tile T+1 landed); MFMA (highA, B23) ----
        if (T < 14) {
            asm volatile("s_waitcnt vmcnt(2)" ::: "memory");
        } else {
            asm volatile("s_waitcnt vmcnt(0)" ::: "memory");
        }
        BAR1();
        { constexpr int JB = 2; MFMA8(4, ph0, ph1); }
        BAR2();
    }
#undef STGA
#undef STGB
#undef STGAH
#undef STGBF
#undef MFMA8
#undef BAR1
#undef BAR2

    // ==== epilogue: wave = one (type, head); natural col order ====
    // acc[i][j]: row = bm*256 + (i>>2)*128 + wm*64 + (i&3)*16 + q4*4 + rr;
    //            col = bn*192 + wn*64 + j*16 + m16
    const int colbase = bn * 192 + wn * 64;
    const int type = colbase >> 10;            // 0=Q 1=K 2=V
    const int h = (colbase & 1023) >> 6;

    if (type == 2) {
        // V transposed: Vt[bh][d][s]; lane's rr=0..3 are 4 consecutive s -> 8B store
#pragma unroll
        for (int i = 0; i < 8; i++) {
            int sr = bm * 256 + (i >> 2) * 128 + wm * 64 + (i & 3) * 16 + q4 * 4;
            int b = sr >> 11, sl = sr & 2047;
            size_t ob = (size_t)(b * 16 + h) * 64 * 2048;
#pragma unroll
            for (int j = 0; j < 4; j++) {
                int d = j * 16 + m16;
                ushort4 o;
                o.x = f2bf(acc[i][j][0]);
                o.y = f2bf(acc[i][j][1]);
                o.z = f2bf(acc[i][j][2]);
                o.w = f2bf(acc[i][j][3]);
                *(ushort4*)&Vt[ob + (size_t)d * 2048 + sl] = o;
            }
        }
    } else {
        u16* dst = (type == 0) ? Q : Kd;
        const float qs = (type == 0) ? 0.1803368801f /*0.125*log2(e)*/ : 1.0f;
#pragma unroll
        for (int i = 0; i < 8; i++)
#pragma unroll
            for (int rr = 0; rr < 4; rr++) {
                int r = bm * 256 + (i >> 2) * 128 + wm * 64 + (i & 3) * 16 + q4 * 4 + rr;
                int b = r >> 11, s = r & 2047;
                size_t ob = ((size_t)((b * 16 + h) * 2048 + s)) * 64;
#pragma unroll
                for (int j2 = 0; j2 < 2; j2++) {
                    int d = j2 * 16 + m16;                 // d in [0,32)
                    float cs = cosT[s * 32 + d];
                    float sn = sinT[s * 32 + d];
                    float x1 = acc[i][j2][rr];
                    float x2 = acc[i][j2 + 2][rr];
                    dst[ob + d]      = f2bf((x1 * cs - x2 * sn) * qs);
                    dst[ob + d + 32] = f2bf((x2 * cs + x1 * sn) * qs);
                }
            }
    }
}

// ---------------- out-proj GEMM: C[M,N] fp32 = A[M,K] @ Bt[N,K]^T ----------------
// 1D grid 256, chunked XCD swizzle (256 = 8*32): each XCD gets 4 bm-panels (1MB)
// + full Bt (2MB) -> 3MB L2-resident, Bt/A fetched once per XCD.
__global__ void __launch_bounds__(256) gemm_out(const u16* __restrict__ A,
                                                const u16* __restrict__ Bt,
                                                float* __restrict__ C) {
    __shared__ __align__(16) u16 As[3 * 128 * 32];
    __shared__ __align__(16) u16 Bs[3 * 128 * 32];
    GemmCtx cx;
    const int hw = blockIdx.x;
    const int orig = (hw & 7) * 32 + (hw >> 3);   // bijective: 256 % 8 == 0
    const int bm = orig >> 3, bn = orig & 7;
    gemm_loop<1024>(A, Bt, bm, bn, cx, As, Bs);
    const int N = 1024;
#pragma unroll
    for (int i = 0; i < 4; i++)
#pragma unroll
        for (int j = 0; j < 4; j++)
#pragma unroll
            for (int rr = 0; rr < 4; rr++) {
                int row = bm * 128 + cx.wm * 64 + i * 16 + cx.q4 * 4 + rr;
                int col = bn * 128 + cx.wn * 64 + j * 16 + cx.m16;
                C[(size_t)row * N + col] = cx.acc[i][j][rr];
            }
}

// ---------------- causal flash attention: 512 blocks, ONE supertile per block ----------------
// 1D grid 512, 2 blocks/CU (16 waves/CU). bid<256: st = 15-(bid>>5) (heavy first),
// bh = bid&31; bid>=256: st = (bid-256)>>5 (light). Round-robin co-locates bid c and
// c+256 on one CU: st pair sums to 15 -> 34 tiles/CU, same bh -> K/V L2-shared.
// Each wave owns one 16-q-row group; per-thread staging 16B K + 16B V per tile.
// S^T = mfma(K_frag, Q_frag); fixed exponent offset M=24; 1 barrier/tile.
__global__ void __launch_bounds__(512) attn_kernel(const u16* __restrict__ Q,
                                                   const u16* __restrict__ Kg_,
                                                   const u16* __restrict__ Vtg_,
                                                   u16* __restrict__ O) {
    __shared__ __align__(16) u16 Ks[2][64][72];     // [buf][key][d]
    __shared__ __align__(16) u16 Vs[2][64][72];     // [buf][d][key]
    __shared__ __align__(16) u16 Pt[8][16][72];     // [wave][q][key]
    const int t = threadIdx.x, w = t >> 6;
    const int m16 = t & 15, q4 = (t & 63) >> 4;
    const int bid = blockIdx.x;
    const int c = bid & 255;
    const int st = (bid < 256) ? (15 - (c >> 5)) : (c >> 5);
    const int bh = c & 31;
    const size_t base = (size_t)bh * 2048 * 64;
    const int b = bh >> 4, h = bh & 15;
    const int skey = t >> 3, sc = (t & 7) * 8;      // 16B staging per thread

    const int qrow = st * 128 + w * 16 + m16;
    const u16* Qg = Q + base + (size_t)qrow * 64;
    bf16x8 qf0 = *(const bf16x8*)(Qg + q4 * 8);
    bf16x8 qf1 = *(const bf16x8*)(Qg + 32 + q4 * 8);

    f32x4 occ[4];
#pragma unroll
    for (int dc = 0; dc < 4; dc++) occ[dc] = zero4();
    float li = 0.f;

    const int jtmax = 2 * st + 1;
    const int jd = 2 * st + (w >> 2);   // this wave's diagonal tile

    const u16* Kb0 = Kg_ + base + skey * 64 + sc;            // + jt*4096
    const u16* Vt0 = Vtg_ + base + (size_t)skey * 2048 + sc; // + jt*64
    uint4 ka = *(const uint4*)(Kb0);
    uint4 va = *(const uint4*)(Vt0);

#pragma unroll 1
    for (int jt = 0; jt <= jtmax; jt++) {
        const int bi = jt & 1;
        *(uint4*)&Ks[bi][skey][sc] = ka;
        *(uint4*)&Vs[bi][skey][sc] = va;
        if (jt < jtmax) {
            ka = *(const uint4*)(Kb0 + (size_t)(jt + 1) * 4096);
            va = *(const uint4*)(Vt0 + (size_t)(jt + 1) * 64);
        }
        __syncthreads();   // single barrier per tile

        if (jt <= jd) {    // wave-uniform activity
            // S^T = K @ Q^T : col(m16)=q, key = cc*16 + q4*4 + rr (log2 domain)
            f32x4 stv[4];
#pragma unroll
            for (int cc = 0; cc < 4; cc++) stv[cc] = zero4();
#pragma unroll
            for (int cc = 0; cc < 4; cc++) {
                bf16x8 kf0 = *(const bf16x8*)&Ks[bi][cc * 16 + m16][q4 * 8];
                bf16x8 kf1 = *(const bf16x8*)&Ks[bi][cc * 16 + m16][32 + q4 * 8];
                stv[cc] = __builtin_amdgcn_mfma_f32_16x16x32_bf16(kf0, qf0, stv[cc], 0, 0, 0);
                stv[cc] = __builtin_amdgcn_mfma_f32_16x16x32_bf16(kf1, qf1, stv[cc], 0, 0, 0);
            }

            float pv[4][4];
#pragma unroll
            for (int cc = 0; cc < 4; cc++)
#pragma unroll
                for (int rr = 0; rr < 4; rr++) pv[cc][rr] = stv[cc][rr];
            if (jt == jd) {   // diagonal: mask key > q (lane-local q)
                const int ql = qrow - 64 * jt;
#pragma unroll
                for (int cc = 0; cc < 4; cc++)
#pragma unroll
                    for (int rr = 0; rr < 4; rr++)
                        if (cc * 16 + q4 * 4 + rr > ql) pv[cc][rr] = -1e30f;
            }

            // fixed-max softmax: p = 2^(s' - 24)
#pragma unroll
            for (int cc = 0; cc < 4; cc++) {
                float p0 = ex2(pv[cc][0] - 24.f);
                float p1 = ex2(pv[cc][1] - 24.f);
                float p2 = ex2(pv[cc][2] - 24.f);
                float p3 = ex2(pv[cc][3] - 24.f);
                li += (p0 + p1) + (p2 + p3);
                *(uint2*)&Pt[w][m16][cc * 16 + q4 * 4] = make_uint2(pk2(p0, p1), pk2(p2, p3));
            }

            // O^T += V^T @ P^T
#pragma unroll
            for (int ks = 0; ks < 2; ks++) {
                bf16x8 pf = *(const bf16x8*)&Pt[w][m16][ks * 32 + q4 * 8];
#pragma unroll
                for (int dc = 0; dc < 4; dc++) {
                    bf16x8 vf = *(const bf16x8*)&Vs[bi][dc * 16 + m16][ks * 32 + q4 * 8];
                    occ[dc] = __builtin_amdgcn_mfma_f32_16x16x32_bf16(vf, pf, occ[dc], 0, 0, 0);
                }
            }
        }
    }

    // epilogue: lane owns q-row qrow; d = dc*16 + q4*4 + rr
    li += __shfl_xor(li, 16);
    li += __shfl_xor(li, 32);
    float rli = 1.0f / li;
    u16* Op = O + ((size_t)(b * 2048 + qrow)) * 1024 + h * 64 + q4 * 4;
#pragma unroll
    for (int dc = 0; dc < 4; dc++) {
        ushort4 o;
        o.x = f2bf(occ[dc][0] * rli);
        o.y = f2bf(occ[dc][1] * rli);
        o.z = f2bf(occ[dc][2] * rli);
        o.w = f2bf(occ[dc][3] * rli);
        *(ushort4*)(Op + dc * 16) = o;
    }
}

extern "C" void kernel_launch(void* const* d_in, const int* in_sizes, int n_in,
                              void* d_out, int out_size, void* d_ws, size_t ws_size,
                              hipStream_t stream) {
    const float* hs   = (const float*)d_in[0];
    const float* Wqkv = (const float*)d_in[2];
    const float* Wo   = (const float*)d_in[3];
    float* out = (float*)d_out;

    const int BS = 4096;
    const int H = 1024, N3 = 3072;
    const int SH = 32 * 2048 * 64;

    u16* Xb    = (u16*)d_ws;                 // [4096,1024]
    u16* Wqkvt = Xb + (size_t)BS * H;        // [3072,1024]
    u16* Wot   = Wqkvt + (size_t)N3 * H;     // [1024,1024]
    u16* Qb    = Wot + (size_t)H * H;        // [bh][s][d]
    u16* Kb    = Qb + SH;
    u16* Vtb   = Kb + SH;                    // [bh][d][s] (written transposed)
    u16* AOb   = Vtb + SH;                   // [4096,1024] bf16
    float* cosT = (float*)(AOb + (size_t)BS * H);   // [2048][32]
    float* sinT = cosT + 2048 * 32;

    prep<<<8448, 256, 0, stream>>>(hs, Xb, Wqkv, Wqkvt, Wo, Wot, cosT, sinT);

    gemm_qkv<<<256, 384, 0, stream>>>(Xb, Wqkvt, cosT, sinT, Qb, Kb, Vtb);

    attn_kernel<<<512, 512, 0, stream>>>(Qb, Kb, Vtb, AOb);

    gemm_out<<<256, 256, 0, stream>>>(AOb, Wot, out);
}